// Round 1
// baseline (220.337 us; speedup 1.0000x reference)
//
#include <hip/hip_runtime.h>
#include <math.h>

#define Tt 1024
#define Dd 1024
#define Hh 16
#define DHh 64
#define MAXPOS 64
#define BTt 2048

typedef short short8 __attribute__((ext_vector_type(8)));
typedef float floatx4 __attribute__((ext_vector_type(4)));

#define MFMA16 __builtin_amdgcn_mfma_f32_16x16x32_bf16

__device__ __forceinline__ unsigned short f2bf(float f) {
    unsigned u;
    __builtin_memcpy(&u, &f, 4);
    u = (u + 0x7FFFu + ((u >> 16) & 1u)) >> 16;
    return (unsigned short)u;
}
__device__ __forceinline__ float bf2fs(short s) {
    unsigned u = ((unsigned)(unsigned short)s) << 16;
    float f;
    __builtin_memcpy(&f, &u, 4);
    return f;
}
// fast sigmoid: v_rcp_f32 instead of IEEE div (~1 ulp; threshold margin is 4x)
__device__ __forceinline__ float fsigm(float x) {
    return __builtin_amdgcn_rcpf(1.f + __expf(-x));
}

// ---------------- fp32 -> bf16 pre-conversion (x + 4 weights) -------------------
__global__ __launch_bounds__(256) void conv_bf16(
    const float* __restrict__ x,  const float* __restrict__ W0,
    const float* __restrict__ W1, const float* __restrict__ W2,
    const float* __restrict__ W3,
    short* __restrict__ xb, short* __restrict__ w0b, short* __restrict__ w1b,
    short* __restrict__ w2b, short* __restrict__ w3b)
{
    const float* src; short* dst; int n;
    switch (blockIdx.y) {
        case 0:  src = x;  dst = xb;  n = BTt * Dd; break;
        case 1:  src = W0; dst = w0b; n = Dd * Dd;  break;
        case 2:  src = W1; dst = w1b; n = Dd * Dd;  break;
        case 3:  src = W2; dst = w2b; n = Dd * Dd;  break;
        default: src = W3; dst = w3b; n = Dd * Dd;  break;
    }
    int idx = (blockIdx.x * 256 + threadIdx.x) * 8;
    if (idx >= n) return;
    floatx4 a0 = *(const floatx4*)&src[idx];
    floatx4 a1 = *(const floatx4*)&src[idx + 4];
    short8 s;
    for (int e = 0; e < 4; ++e) {
        s[e]     = (short)f2bf(a0[e]);
        s[e + 4] = (short)f2bf(a1[e]);
    }
    *(short8*)&dst[idx] = s;
}

// ------------- MFMA GEMM: C = A[M,K] * W[N,K]^T + bias (bf16 in, bf16 MFMA)
// R11-proven staging: padded LDS (stride 72), coalesced short8 loads via VGPR.
#define BM 128
#define BN 128
#define BKK 64
#define LDSS 72

template <int MODE>   // 0: fp32 out, 1: bf16 out
__device__ __forceinline__ void gemm_body(const short* __restrict__ A,
                                          const short* __restrict__ W,
                                          const float* __restrict__ bias,
                                          void* __restrict__ Cout,
                                          int N, int K)
{
    __shared__ __align__(16) short Ash[BM * LDSS];
    __shared__ __align__(16) short Bsh[BN * LDSS];
    const int t = threadIdx.x;
    const int lane = t & 63, wave = t >> 6;
    const int wm = wave >> 1, wn = wave & 1;
    const int quad = lane >> 4, l16 = lane & 15;
    const int row0 = blockIdx.x * BM, col0 = blockIdx.y * BN;

    floatx4 acc[4][4];
    for (int a = 0; a < 4; ++a)
        for (int b2 = 0; b2 < 4; ++b2)
            acc[a][b2] = (floatx4){0.f, 0.f, 0.f, 0.f};

    for (int kb = 0; kb < K; kb += BKK) {
        __syncthreads();
        for (int q2 = 0; q2 < 4; ++q2) {
            int ch = t + 256 * q2;
            int r = ch >> 3, c = ch & 7;
            *(short8*)&Ash[r * LDSS + c * 8] =
                *(const short8*)&A[(size_t)(row0 + r) * K + kb + c * 8];
            *(short8*)&Bsh[r * LDSS + c * 8] =
                *(const short8*)&W[(size_t)(col0 + r) * K + kb + c * 8];
        }
        __syncthreads();
        for (int ks = 0; ks < BKK / 32; ++ks) {
            short8 af[4], bfr[4];
            for (int tm = 0; tm < 4; ++tm)
                af[tm] = *(short8*)&Ash[(wm * 64 + tm * 16 + l16) * LDSS + ks * 32 + quad * 8];
            for (int tn = 0; tn < 4; ++tn)
                bfr[tn] = *(short8*)&Bsh[(wn * 64 + tn * 16 + l16) * LDSS + ks * 32 + quad * 8];
            for (int tm = 0; tm < 4; ++tm)
                for (int tn = 0; tn < 4; ++tn)
                    acc[tm][tn] = MFMA16(af[tm], bfr[tn], acc[tm][tn], 0, 0, 0);
        }
    }
    for (int tm = 0; tm < 4; ++tm)
        for (int tn = 0; tn < 4; ++tn) {
            int col = col0 + wn * 64 + tn * 16 + l16;
            float bv = bias[col];
            for (int r = 0; r < 4; ++r) {
                int row = row0 + wm * 64 + tm * 16 + quad * 4 + r;
                float v = acc[tm][tn][r] + bv;
                if (MODE == 0) ((float*)Cout)[(size_t)row * N + col] = v;
                else           ((short*)Cout)[(size_t)row * N + col] = (short)f2bf(v);
            }
        }
}

__global__ __launch_bounds__(256) void gemm_qkv(
    const short* __restrict__ xb,
    const short* __restrict__ Wqb, const short* __restrict__ Wkb,
    const short* __restrict__ Wvb,
    const float* __restrict__ bq, const float* __restrict__ bk,
    const float* __restrict__ bv,
    short* __restrict__ Qb, short* __restrict__ Kb, short* __restrict__ Vrow)
{
    if (blockIdx.z == 0)      gemm_body<1>(xb, Wqb, bq, Qb, Dd, Dd);
    else if (blockIdx.z == 1) gemm_body<1>(xb, Wkb, bk, Kb, Dd, Dd);
    else                      gemm_body<1>(xb, Wvb, bv, Vrow, Dd, Dd);
}

__global__ __launch_bounds__(256) void gemm_o(
    const short* __restrict__ A, const short* __restrict__ W,
    const float* __restrict__ bias, float* __restrict__ C)
{
    gemm_body<0>(A, W, bias, C, Dd, Dd);
}

// ------- merged kernel: blockIdx.x < 256 -> gate sums; >= 256 -> V transpose ----
// Gates: sigmoid-sums reduced DIRECTLY from MFMA C-layout registers via
// shfl_xor butterflies (no S round-trip through LDS). LDS ~23.6 KB.
__global__ __launch_bounds__(256) void vt_gates(
    const short* __restrict__ Q, const short* __restrict__ K,
    const short* __restrict__ Vrow, short* __restrict__ Vt,
    float* __restrict__ gts)
{
    __shared__ __align__(16) short Qt[32 * 72];
    __shared__ __align__(16) short KV[128 * 72];   // vt branch reuses as 64x72 tile
    __shared__ float redg[32 * 4];

    const int t = threadIdx.x;

    if (blockIdx.x >= 256) {
        // ---- V transpose: Vt[b][d][j] = Vrow[b][j][d], 64x64 tiles ----
        const int j0 = (blockIdx.x - 256) * 64, d0 = blockIdx.y * 64, b = blockIdx.z;
        short* L = KV;
        for (int s = 0; s < 2; ++s) {
            int c = t * 2 + s;
            int jr = c >> 3, c8 = c & 7;
            *(short8*)&L[jr * 72 + c8 * 8] =
                *(const short8*)&Vrow[((size_t)(b * Tt + j0 + jr)) * Dd + d0 + c8 * 8];
        }
        __syncthreads();
        for (int s = 0; s < 2; ++s) {
            int c = t * 2 + s;
            int dr = c >> 3, c8 = c & 7;
            short8 v;
            for (int e = 0; e < 8; ++e) v[e] = L[(c8 * 8 + e) * 72 + dr];
            *(short8*)&Vt[((size_t)(b * Dd + d0 + dr)) * Tt + j0 + c8 * 8] = v;
        }
        return;
    }

    // ---- gate sums: per-(row, j-tile) sigmoid sums, register-reduced ----
    const int it = blockIdx.x >> 3, jt = blockIdx.x & 7;
    const int h = blockIdx.y, b = blockIdx.z;
    const int i0 = it * 32, j0 = jt * 128;
    const int lane = t & 63, wave = t >> 6;
    const int quad = lane >> 4, l16 = lane & 15;

    float* g = &gts[(((size_t)(b * Hh + h)) * Tt + i0) * 8 + jt];
    if (j0 > i0 + 31) {                     // tile fully masked
        if (t < 32) g[t * 8] = 0.f;
        return;
    }

    const float inv_scale = 0.125f;

    {
        int r = t >> 3, c = t & 7;
        *(short8*)&Qt[r * 72 + c * 8] =
            *(const short8*)&Q[((size_t)(b * Tt + i0 + r)) * Dd + h * DHh + c * 8];
    }
    for (int e = 0; e < 4; ++e) {
        int ch = t + 256 * e;
        int jr = ch >> 3, c = ch & 7;
        *(short8*)&KV[jr * 72 + c * 8] =
            *(const short8*)&K[((size_t)(b * Tt + j0 + jr)) * Dd + h * DHh + c * 8];
    }
    __syncthreads();

    int ntA = 2 * wave, ntB = ntA + 1;
    floatx4 c00 = {0,0,0,0}, c01 = {0,0,0,0}, c10 = {0,0,0,0}, c11 = {0,0,0,0};
    for (int ks = 0; ks < 2; ++ks) {
        short8 a0 = *(short8*)&Qt[(l16) * 72 + ks * 32 + quad * 8];
        short8 a1 = *(short8*)&Qt[(16 + l16) * 72 + ks * 32 + quad * 8];
        short8 b0 = *(short8*)&KV[(ntA * 16 + l16) * 72 + ks * 32 + quad * 8];
        short8 b1 = *(short8*)&KV[(ntB * 16 + l16) * 72 + ks * 32 + quad * 8];
        c00 = MFMA16(a0, b0, c00, 0, 0, 0);
        c01 = MFMA16(a0, b1, c01, 0, 0, 0);
        c10 = MFMA16(a1, b0, c10, 0, 0, 0);
        c11 = MFMA16(a1, b1, c11, 0, 0, 0);
    }
    // C/D layout: row m = quad*4+r, col n = l16. Mask, sigmoid, reduce over cols.
    const int jA = j0 + ntA * 16 + l16;
    const int jB = j0 + ntB * 16 + l16;
    for (int r = 0; r < 4; ++r) {
        int m0 = i0 + quad * 4 + r;
        int m1 = m0 + 16;
        float v0 = ((jA <= m0) ? fsigm(c00[r] * inv_scale) : 0.f)
                 + ((jB <= m0) ? fsigm(c01[r] * inv_scale) : 0.f);
        float v1 = ((jA <= m1) ? fsigm(c10[r] * inv_scale) : 0.f)
                 + ((jB <= m1) ? fsigm(c11[r] * inv_scale) : 0.f);
        for (int o = 1; o < 16; o <<= 1) {
            v0 += __shfl_xor(v0, o, 64);
            v1 += __shfl_xor(v1, o, 64);
        }
        if (l16 == 0) {
            redg[(quad * 4 + r) * 4 + wave]      = v0;
            redg[(16 + quad * 4 + r) * 4 + wave] = v1;
        }
    }
    __syncthreads();
    if (t < 32) {
        float s2 = redg[t * 4] + redg[t * 4 + 1] + redg[t * 4 + 2] + redg[t * 4 + 3];
        g[t * 8] = s2;
    }
}

// ---------------- fused attn: scores + no-max softmax + PV (single pass) --------
// R12: Pb aliased INTO the S buffer (per-thread-disjoint live ranges): each
// thread's 16 packed-bf16 P values overwrite the low half of the 16 f32 S
// values it has just consumed. P[r][j] lives at short idx r*264+(j>>4)*32+(j&15).
// LDS: 48.5 KB -> 39.8 KB => 4 blocks/CU (was 3). Softmax-phase accesses go
// through the short-typed view uniformly so the alias is TBAA-safe.
__global__ __launch_bounds__(256) void cope_attn(
    const short* __restrict__ Q, const short* __restrict__ K,
    const short* __restrict__ Vt, const float* __restrict__ PE,
    const float* __restrict__ gts, short* __restrict__ AOb)
{
    const int it = (int)gridDim.x - 1 - (int)blockIdx.x;   // heavy tiles first
    const int h = blockIdx.y, b = blockIdx.z;
    const int i0 = it * 32;
    const int t = threadIdx.x, lane = t & 63, wave = t >> 6;
    const int quad = lane >> 4, l16 = lane & 15;

    // SldS: setup Q tile (short) / S tile (f32, row stride 132 floats) /
    //       P tile (bf16, packed, aliased) -- 16.9 KB
    __shared__ __align__(16) short SldS[32 * 264];
    __shared__ __align__(16) short KV[128 * 72];    // PE / K[128][72] / V[64][136]
    __shared__ short qpeB[32 * 68];
    __shared__ float lrow[32];
    float* Sld = (float*)SldS;

    const float inv_scale = 0.125f;
    const int sr = t >> 3, ss = t & 7, irow = i0 + sr;

    float grow[8];
    {
        const float* gp = &gts[(((size_t)(b * Hh + h)) * Tt + i0 + sr) * 8];
        for (int k = 0; k < 8; ++k) grow[k] = gp[k];
    }
    float tot = 0.f;
    for (int k = 0; k < 8; ++k) tot += grow[k];

    short* QtS = SldS;
    {
        int r = t >> 3, c = t & 7;
        *(short8*)&QtS[r * 72 + c * 8] =
            *(const short8*)&Q[((size_t)(b * Tt + i0 + r)) * Dd + h * DHh + c * 8];
    }
    for (int e = 0; e < 16; ++e) {
        int idx = t + 256 * e;
        int p = idx >> 6, d = idx & 63;
        KV[p * 72 + d] = (short)f2bf(PE[((size_t)h * MAXPOS + p) * DHh + d]);
    }
    __syncthreads();

    short8 qa[2][2];
    for (int rb = 0; rb < 2; ++rb)
        for (int ks = 0; ks < 2; ++ks)
            qa[rb][ks] = *(short8*)&QtS[(rb * 16 + l16) * 72 + ks * 32 + quad * 8];

    // qpe table via MFMA (M=32, N=64, K=64)
    {
        int mt = wave >> 1;
        int ntA = 2 * (wave & 1), ntB = ntA + 1;
        floatx4 c0f = {0, 0, 0, 0}, c1f = {0, 0, 0, 0};
        for (int ks = 0; ks < 2; ++ks) {
            short8 b0 = *(short8*)&KV[(ntA * 16 + l16) * 72 + ks * 32 + quad * 8];
            short8 b1 = *(short8*)&KV[(ntB * 16 + l16) * 72 + ks * 32 + quad * 8];
            c0f = MFMA16(qa[mt][ks], b0, c0f, 0, 0, 0);
            c1f = MFMA16(qa[mt][ks], b1, c1f, 0, 0, 0);
        }
        for (int r = 0; r < 4; ++r) {
            qpeB[(mt * 16 + quad * 4 + r) * 68 + ntA * 16 + l16] = (short)f2bf(c0f[r]);
            qpeB[(mt * 16 + quad * 4 + r) * 68 + ntB * 16 + l16] = (short)f2bf(c1f[r]);
        }
    }

    const int JT = (i0 + 159) >> 7;
    floatx4 o0 = {0, 0, 0, 0}, o1 = {0, 0, 0, 0};
    const int pv_mt = wave >> 1;
    const int pv_ntA = 2 * (wave & 1), pv_ntB = pv_ntA + 1;
    float l_acc = 0.f;
    float baseAcc = 0.f;

    short8 kreg[4];
    for (int e = 0; e < 4; ++e) {
        int ch = t + 256 * e;
        int jr = ch >> 3, c = ch & 7;
        kreg[e] = *(const short8*)&K[((size_t)(b * Tt + jr)) * Dd + h * DHh + c * 8];
    }

    for (int jt = 0; jt < JT; ++jt) {
        const int j0 = jt * 128;
        __syncthreads();                                    // A: KV free
        for (int e = 0; e < 4; ++e) {
            int ch = t + 256 * e;
            int jr = ch >> 3, c = ch & 7;
            *(short8*)&KV[jr * 72 + c * 8] = kreg[e];
        }
        __syncthreads();                                    // B: K staged
        {
            int ntA = 2 * wave, ntB = ntA + 1;
            floatx4 c00 = {0,0,0,0}, c01 = {0,0,0,0}, c10 = {0,0,0,0}, c11 = {0,0,0,0};
            for (int ks = 0; ks < 2; ++ks) {
                short8 b0 = *(short8*)&KV[(ntA * 16 + l16) * 72 + ks * 32 + quad * 8];
                short8 b1 = *(short8*)&KV[(ntB * 16 + l16) * 72 + ks * 32 + quad * 8];
                c00 = MFMA16(qa[0][ks], b0, c00, 0, 0, 0);
                c01 = MFMA16(qa[0][ks], b1, c01, 0, 0, 0);
                c10 = MFMA16(qa[1][ks], b0, c10, 0, 0, 0);
                c11 = MFMA16(qa[1][ks], b1, c11, 0, 0, 0);
            }
            for (int r = 0; r < 4; ++r) {
                Sld[(quad * 4 + r) * 132 + ntA * 16 + l16] = c00[r];
                Sld[(quad * 4 + r) * 132 + ntB * 16 + l16] = c01[r];
                Sld[(16 + quad * 4 + r) * 132 + ntA * 16 + l16] = c10[r];
                Sld[(16 + quad * 4 + r) * 132 + ntB * 16 + l16] = c11[r];
            }
        }
        __syncthreads();                                    // C: S ready
        short8 vreg[4];
        for (int e = 0; e < 4; ++e) {
            int ch = t + 256 * e;
            int d = ch >> 4, c = ch & 15;
            vreg[e] = *(const short8*)&Vt[((size_t)(b * Dd + h * DHh + d)) * Tt + j0 + c * 8];
        }
        if (jt + 1 < JT) {
            for (int e = 0; e < 4; ++e) {
                int ch = t + 256 * e;
                int jr = ch >> 3, c = ch & 7;
                kreg[e] = *(const short8*)&K[((size_t)(b * Tt + j0 + 128 + jr)) * Dd + h * DHh + c * 8];
            }
        }
        {
            // read own 16 S floats (short-typed loads, bit-cast: TBAA-safe alias)
            floatx4 qv[4];
            for (int q4 = 0; q4 < 4; ++q4) {
                short8 qraw = *(short8*)&SldS[sr * 264 + ss * 32 + q4 * 8];
                __builtin_memcpy(&qv[q4], &qraw, 16);
            }
            float gt[16];
            float gs = 0.f;
            for (int e = 0; e < 16; ++e) {
                int j = j0 + ss * 16 + e;
                float qk = qv[e >> 2][e & 3];
                float g = (j <= irow) ? fsigm(qk * inv_scale) : 0.f;
                gt[e] = g;
                gs += g;
            }
            float inc = gs;
            for (int d2 = 1; d2 < 8; d2 <<= 1) {
                float n = __shfl_up(inc, d2, 64);
                if ((lane & 7) >= d2) inc += n;
            }
            float base = baseAcc + (inc - gs);
            float run = 0.f;
            short8 p0, p1;
            for (int e = 0; e < 16; ++e) {
                run += gt[e];
                int j = j0 + ss * 16 + e;
                float pos = tot - (base + run);
                pos = fminf(fmaxf(pos, 0.f), 63.f);
                float pf = floorf(pos);
                float al = pos - pf;
                int fi = (int)pf;
                int ci = fi + 1; if (ci > 63) ci = 63;
                float qp = (1.f - al) * bf2fs(qpeB[sr * 68 + fi]) + al * bf2fs(qpeB[sr * 68 + ci]);
                float qk = qv[e >> 2][e & 3];
                float p = (j <= irow) ? __expf((qk + qp) * inv_scale) : 0.f;
                if (e < 8) p0[e] = (short)f2bf(p); else p1[e - 8] = (short)f2bf(p);
                l_acc += p;
            }
            // P overwrites the low half of this thread's OWN consumed S region
            *(short8*)&SldS[sr * 264 + ss * 32]     = p0;
            *(short8*)&SldS[sr * 264 + ss * 32 + 8] = p1;
            baseAcc += grow[jt];
        }
        for (int e = 0; e < 4; ++e) {
            int ch = t + 256 * e;
            int d = ch >> 4, c = ch & 15;
            *(short8*)&KV[d * 136 + c * 8] = vreg[e];
        }
        __syncthreads();                                    // D: P + V ready
        for (int ks = 0; ks < 4; ++ks) {
            short8 a  = *(short8*)&SldS[(pv_mt * 16 + l16) * 264 + ks * 64
                                        + ((quad >> 1) << 5) + ((quad & 1) << 3)];
            short8 b0 = *(short8*)&KV[(pv_ntA * 16 + l16) * 136 + ks * 32 + quad * 8];
            short8 b1 = *(short8*)&KV[(pv_ntB * 16 + l16) * 136 + ks * 32 + quad * 8];
            o0 = MFMA16(a, b0, o0, 0, 0, 0);
            o1 = MFMA16(a, b1, o1, 0, 0, 0);
        }
    }
    float lr = l_acc;
    for (int d2 = 4; d2 >= 1; d2 >>= 1) lr += __shfl_xor(lr, d2, 64);
    if (ss == 0) lrow[sr] = lr;
    __syncthreads();
    for (int r = 0; r < 4; ++r) {
        int row = pv_mt * 16 + quad * 4 + r;
        float inv = __builtin_amdgcn_rcpf(lrow[row]);
        size_t off = ((size_t)(b * Tt + i0 + row)) * Dd + h * DHh;
        AOb[off + pv_ntA * 16 + l16] = (short)f2bf(o0[r] * inv);
        AOb[off + pv_ntB * 16 + l16] = (short)f2bf(o1[r] * inv);
    }
}

// ---------------- launch ---------------------------------------------------------
extern "C" void kernel_launch(void* const* d_in, const int* in_sizes, int n_in,
                              void* d_out, int out_size, void* d_ws, size_t ws_size,
                              hipStream_t stream)
{
    const float* x  = (const float*)d_in[0];
    const float* Wq = (const float*)d_in[1];
    const float* bq = (const float*)d_in[2];
    const float* Wk = (const float*)d_in[3];
    const float* bk = (const float*)d_in[4];
    const float* Wv = (const float*)d_in[5];
    const float* bv = (const float*)d_in[6];
    const float* Wo = (const float*)d_in[7];
    const float* bo = (const float*)d_in[8];
    const float* pe = (const float*)d_in[9];
    // d_in[10]: causal mask (j > i) — structural, unused

    short* xb   = (short*)d_ws;                         //  4 MB
    short* Wqb  = xb   + (size_t)BTt * Dd;              //  2 MB
    short* Wkb  = Wqb  + (size_t)Dd * Dd;               //  2 MB
    short* Wvb  = Wkb  + (size_t)Dd * Dd;               //  2 MB
    short* Wob  = Wvb  + (size_t)Dd * Dd;               //  2 MB
    short* Qb   = Wob  + (size_t)Dd * Dd;               //  4 MB
    short* Kb   = Qb   + (size_t)BTt * Dd;              //  4 MB
    short* Vrow = Kb   + (size_t)BTt * Dd;              //  4 MB
    short* Vtg  = Vrow + (size_t)BTt * Dd;              //  4 MB
    short* AOb  = Vtg  + (size_t)BTt * Dd;              //  4 MB
    float* gts  = (float*)(AOb + (size_t)BTt * Dd);     //  1 MB

    dim3 gc(BTt * Dd / 8 / 256, 5);
    conv_bf16<<<gc, 256, 0, stream>>>(x, Wq, Wk, Wv, Wo, xb, Wqb, Wkb, Wvb, Wob);

    dim3 gq(BTt / BM, Dd / BN, 3);
    gemm_qkv<<<gq, 256, 0, stream>>>(xb, Wqb, Wkb, Wvb, bq, bk, bv, Qb, Kb, Vrow);

    dim3 gg(272, Hh, 2);    // x<256: gate sums; x>=256: V transpose (y = d-tile)
    vt_gates<<<gg, 256, 0, stream>>>(Qb, Kb, Vrow, Vtg, gts);

    dim3 ga(Tt / 32, Hh, 2);
    cope_attn<<<ga, 256, 0, stream>>>(Qb, Kb, Vtg, pe, gts, AOb);

    dim3 go(BTt / BM, Dd / BN, 1);
    gemm_o<<<go, 256, 0, stream>>>(AOb, Wob, bo, (float*)d_out);
}

// Round 2
// 200.895 us; speedup vs baseline: 1.0968x; 1.0968x over previous
//
#include <hip/hip_runtime.h>
#include <math.h>

#define Tt 1024
#define Dd 1024
#define Hh 16
#define DHh 64
#define MAXPOS 64
#define BTt 2048

typedef short short8 __attribute__((ext_vector_type(8)));
typedef float floatx4 __attribute__((ext_vector_type(4)));

#define MFMA16 __builtin_amdgcn_mfma_f32_16x16x32_bf16

__device__ __forceinline__ unsigned short f2bf(float f) {
    unsigned u;
    __builtin_memcpy(&u, &f, 4);
    u = (u + 0x7FFFu + ((u >> 16) & 1u)) >> 16;
    return (unsigned short)u;
}
__device__ __forceinline__ float bf2fs(short s) {
    unsigned u = ((unsigned)(unsigned short)s) << 16;
    float f;
    __builtin_memcpy(&f, &u, 4);
    return f;
}
// fast sigmoid: v_rcp_f32 instead of IEEE div (~1 ulp; threshold margin is 4x)
__device__ __forceinline__ float fsigm(float x) {
    return __builtin_amdgcn_rcpf(1.f + __expf(-x));
}

// ---------------- fp32 -> bf16 pre-conversion (x + 4 weights) -------------------
__global__ __launch_bounds__(256) void conv_bf16(
    const float* __restrict__ x,  const float* __restrict__ W0,
    const float* __restrict__ W1, const float* __restrict__ W2,
    const float* __restrict__ W3,
    short* __restrict__ xb, short* __restrict__ w0b, short* __restrict__ w1b,
    short* __restrict__ w2b, short* __restrict__ w3b)
{
    const float* src; short* dst; int n;
    switch (blockIdx.y) {
        case 0:  src = x;  dst = xb;  n = BTt * Dd; break;
        case 1:  src = W0; dst = w0b; n = Dd * Dd;  break;
        case 2:  src = W1; dst = w1b; n = Dd * Dd;  break;
        case 3:  src = W2; dst = w2b; n = Dd * Dd;  break;
        default: src = W3; dst = w3b; n = Dd * Dd;  break;
    }
    int idx = (blockIdx.x * 256 + threadIdx.x) * 8;
    if (idx >= n) return;
    floatx4 a0 = *(const floatx4*)&src[idx];
    floatx4 a1 = *(const floatx4*)&src[idx + 4];
    short8 s;
    for (int e = 0; e < 4; ++e) {
        s[e]     = (short)f2bf(a0[e]);
        s[e + 4] = (short)f2bf(a1[e]);
    }
    *(short8*)&dst[idx] = s;
}

// ------------- MFMA GEMM: C = A[M,K] * W[N,K]^T + bias (bf16 in, bf16 MFMA)
// R11-proven staging: padded LDS (stride 72), coalesced short8 loads via VGPR.
#define BM 128
#define BN 128
#define BKK 64
#define LDSS 72

template <int MODE>   // 0: fp32 out, 1: bf16 out
__device__ __forceinline__ void gemm_body(const short* __restrict__ A,
                                          const short* __restrict__ W,
                                          const float* __restrict__ bias,
                                          void* __restrict__ Cout,
                                          int N, int K)
{
    __shared__ __align__(16) short Ash[BM * LDSS];
    __shared__ __align__(16) short Bsh[BN * LDSS];
    const int t = threadIdx.x;
    const int lane = t & 63, wave = t >> 6;
    const int wm = wave >> 1, wn = wave & 1;
    const int quad = lane >> 4, l16 = lane & 15;
    const int row0 = blockIdx.x * BM, col0 = blockIdx.y * BN;

    floatx4 acc[4][4];
    for (int a = 0; a < 4; ++a)
        for (int b2 = 0; b2 < 4; ++b2)
            acc[a][b2] = (floatx4){0.f, 0.f, 0.f, 0.f};

    for (int kb = 0; kb < K; kb += BKK) {
        __syncthreads();
        for (int q2 = 0; q2 < 4; ++q2) {
            int ch = t + 256 * q2;
            int r = ch >> 3, c = ch & 7;
            *(short8*)&Ash[r * LDSS + c * 8] =
                *(const short8*)&A[(size_t)(row0 + r) * K + kb + c * 8];
            *(short8*)&Bsh[r * LDSS + c * 8] =
                *(const short8*)&W[(size_t)(col0 + r) * K + kb + c * 8];
        }
        __syncthreads();
        for (int ks = 0; ks < BKK / 32; ++ks) {
            short8 af[4], bfr[4];
            for (int tm = 0; tm < 4; ++tm)
                af[tm] = *(short8*)&Ash[(wm * 64 + tm * 16 + l16) * LDSS + ks * 32 + quad * 8];
            for (int tn = 0; tn < 4; ++tn)
                bfr[tn] = *(short8*)&Bsh[(wn * 64 + tn * 16 + l16) * LDSS + ks * 32 + quad * 8];
            for (int tm = 0; tm < 4; ++tm)
                for (int tn = 0; tn < 4; ++tn)
                    acc[tm][tn] = MFMA16(af[tm], bfr[tn], acc[tm][tn], 0, 0, 0);
        }
    }
    for (int tm = 0; tm < 4; ++tm)
        for (int tn = 0; tn < 4; ++tn) {
            int col = col0 + wn * 64 + tn * 16 + l16;
            float bv = bias[col];
            for (int r = 0; r < 4; ++r) {
                int row = row0 + wm * 64 + tm * 16 + quad * 4 + r;
                float v = acc[tm][tn][r] + bv;
                if (MODE == 0) ((float*)Cout)[(size_t)row * N + col] = v;
                else           ((short*)Cout)[(size_t)row * N + col] = (short)f2bf(v);
            }
        }
}

__global__ __launch_bounds__(256) void gemm_qkv(
    const short* __restrict__ xb,
    const short* __restrict__ Wqb, const short* __restrict__ Wkb,
    const short* __restrict__ Wvb,
    const float* __restrict__ bq, const float* __restrict__ bk,
    const float* __restrict__ bv,
    short* __restrict__ Qb, short* __restrict__ Kb, short* __restrict__ Vrow)
{
    if (blockIdx.z == 0)      gemm_body<1>(xb, Wqb, bq, Qb, Dd, Dd);
    else if (blockIdx.z == 1) gemm_body<1>(xb, Wkb, bk, Kb, Dd, Dd);
    else                      gemm_body<1>(xb, Wvb, bv, Vrow, Dd, Dd);
}

__global__ __launch_bounds__(256) void gemm_o(
    const short* __restrict__ A, const short* __restrict__ W,
    const float* __restrict__ bias, float* __restrict__ C)
{
    gemm_body<0>(A, W, bias, C, Dd, Dd);
}

// ------- merged kernel: blockIdx.x < 256 -> gate sums; >= 256 -> V transpose ----
// Gates: sigmoid-sums reduced DIRECTLY from MFMA C-layout registers via
// shfl_xor butterflies (no S round-trip through LDS). LDS ~23.6 KB.
__global__ __launch_bounds__(256) void vt_gates(
    const short* __restrict__ Q, const short* __restrict__ K,
    const short* __restrict__ Vrow, short* __restrict__ Vt,
    float* __restrict__ gts)
{
    __shared__ __align__(16) short Qt[32 * 72];
    __shared__ __align__(16) short KV[128 * 72];   // vt branch reuses as 64x72 tile
    __shared__ float redg[32 * 4];

    const int t = threadIdx.x;

    if (blockIdx.x >= 256) {
        // ---- V transpose: Vt[b][d][j] = Vrow[b][j][d], 64x64 tiles ----
        const int j0 = (blockIdx.x - 256) * 64, d0 = blockIdx.y * 64, b = blockIdx.z;
        short* L = KV;
        for (int s = 0; s < 2; ++s) {
            int c = t * 2 + s;
            int jr = c >> 3, c8 = c & 7;
            *(short8*)&L[jr * 72 + c8 * 8] =
                *(const short8*)&Vrow[((size_t)(b * Tt + j0 + jr)) * Dd + d0 + c8 * 8];
        }
        __syncthreads();
        for (int s = 0; s < 2; ++s) {
            int c = t * 2 + s;
            int dr = c >> 3, c8 = c & 7;
            short8 v;
            for (int e = 0; e < 8; ++e) v[e] = L[(c8 * 8 + e) * 72 + dr];
            *(short8*)&Vt[((size_t)(b * Dd + d0 + dr)) * Tt + j0 + c8 * 8] = v;
        }
        return;
    }

    // ---- gate sums: per-(row, j-tile) sigmoid sums, register-reduced ----
    const int it = blockIdx.x >> 3, jt = blockIdx.x & 7;
    const int h = blockIdx.y, b = blockIdx.z;
    const int i0 = it * 32, j0 = jt * 128;
    const int lane = t & 63, wave = t >> 6;
    const int quad = lane >> 4, l16 = lane & 15;

    float* g = &gts[(((size_t)(b * Hh + h)) * Tt + i0) * 8 + jt];
    if (j0 > i0 + 31) {                     // tile fully masked
        if (t < 32) g[t * 8] = 0.f;
        return;
    }

    const float inv_scale = 0.125f;

    {
        int r = t >> 3, c = t & 7;
        *(short8*)&Qt[r * 72 + c * 8] =
            *(const short8*)&Q[((size_t)(b * Tt + i0 + r)) * Dd + h * DHh + c * 8];
    }
    for (int e = 0; e < 4; ++e) {
        int ch = t + 256 * e;
        int jr = ch >> 3, c = ch & 7;
        *(short8*)&KV[jr * 72 + c * 8] =
            *(const short8*)&K[((size_t)(b * Tt + j0 + jr)) * Dd + h * DHh + c * 8];
    }
    __syncthreads();

    int ntA = 2 * wave, ntB = ntA + 1;
    floatx4 c00 = {0,0,0,0}, c01 = {0,0,0,0}, c10 = {0,0,0,0}, c11 = {0,0,0,0};
    for (int ks = 0; ks < 2; ++ks) {
        short8 a0 = *(short8*)&Qt[(l16) * 72 + ks * 32 + quad * 8];
        short8 a1 = *(short8*)&Qt[(16 + l16) * 72 + ks * 32 + quad * 8];
        short8 b0 = *(short8*)&KV[(ntA * 16 + l16) * 72 + ks * 32 + quad * 8];
        short8 b1 = *(short8*)&KV[(ntB * 16 + l16) * 72 + ks * 32 + quad * 8];
        c00 = MFMA16(a0, b0, c00, 0, 0, 0);
        c01 = MFMA16(a0, b1, c01, 0, 0, 0);
        c10 = MFMA16(a1, b0, c10, 0, 0, 0);
        c11 = MFMA16(a1, b1, c11, 0, 0, 0);
    }
    // C/D layout: row m = quad*4+r, col n = l16. Mask, sigmoid, reduce over cols.
    const int jA = j0 + ntA * 16 + l16;
    const int jB = j0 + ntB * 16 + l16;
    for (int r = 0; r < 4; ++r) {
        int m0 = i0 + quad * 4 + r;
        int m1 = m0 + 16;
        float v0 = ((jA <= m0) ? fsigm(c00[r] * inv_scale) : 0.f)
                 + ((jB <= m0) ? fsigm(c01[r] * inv_scale) : 0.f);
        float v1 = ((jA <= m1) ? fsigm(c10[r] * inv_scale) : 0.f)
                 + ((jB <= m1) ? fsigm(c11[r] * inv_scale) : 0.f);
        for (int o = 1; o < 16; o <<= 1) {
            v0 += __shfl_xor(v0, o, 64);
            v1 += __shfl_xor(v1, o, 64);
        }
        if (l16 == 0) {
            redg[(quad * 4 + r) * 4 + wave]      = v0;
            redg[(16 + quad * 4 + r) * 4 + wave] = v1;
        }
    }
    __syncthreads();
    if (t < 32) {
        float s2 = redg[t * 4] + redg[t * 4 + 1] + redg[t * 4 + 2] + redg[t * 4 + 3];
        g[t * 8] = s2;
    }
}

// ---------------- fused attn: scores + no-max softmax + PV (single pass) --------
// R13: paired i-tiles. JT(it) = 1 + (it>>2), and JT(bx) + JT(31-bx) == 9 for all
// bx, so one block processes tiles (31-bx) then (bx): every block does exactly 9
// j-tiles of work -> perfect static balance (was: co-resident grid with a 1..8
// spread and a long idle tail, time-avg occupancy 15.7%). Grid x: 32 -> 16.
// No combine needed; phase 1 reuses LDS safely (phase 0's last SldS/KV reads all
// precede its final barrier; only lrow is read after it).
__global__ __launch_bounds__(256) void cope_attn(
    const short* __restrict__ Q, const short* __restrict__ K,
    const short* __restrict__ Vt, const float* __restrict__ PE,
    const float* __restrict__ gts, short* __restrict__ AOb)
{
    const int h = blockIdx.y, b = blockIdx.z;
    const int t = threadIdx.x, lane = t & 63, wave = t >> 6;
    const int quad = lane >> 4, l16 = lane & 15;

    // SldS: setup Q tile (short) / S tile (f32, row stride 132 floats) /
    //       P tile (bf16, packed, aliased) -- 16.9 KB
    __shared__ __align__(16) short SldS[32 * 264];
    __shared__ __align__(16) short KV[128 * 72];    // PE / K[128][72] / V[64][136]
    __shared__ short qpeB[32 * 68];
    __shared__ float lrow[32];
    float* Sld = (float*)SldS;

    const float inv_scale = 0.125f;
    const int sr = t >> 3, ss = t & 7;

    for (int phase = 0; phase < 2; ++phase) {
        const int it = (phase == 0) ? (31 - (int)blockIdx.x) : (int)blockIdx.x;
        const int i0 = it * 32;
        const int irow = i0 + sr;

        float grow[8];
        {
            const float* gp = &gts[(((size_t)(b * Hh + h)) * Tt + i0 + sr) * 8];
            for (int k = 0; k < 8; ++k) grow[k] = gp[k];
        }
        float tot = 0.f;
        for (int k = 0; k < 8; ++k) tot += grow[k];

        short* QtS = SldS;
        {
            int r = t >> 3, c = t & 7;
            *(short8*)&QtS[r * 72 + c * 8] =
                *(const short8*)&Q[((size_t)(b * Tt + i0 + r)) * Dd + h * DHh + c * 8];
        }
        for (int e = 0; e < 16; ++e) {
            int idx = t + 256 * e;
            int p = idx >> 6, d = idx & 63;
            KV[p * 72 + d] = (short)f2bf(PE[((size_t)h * MAXPOS + p) * DHh + d]);
        }
        __syncthreads();

        short8 qa[2][2];
        for (int rb = 0; rb < 2; ++rb)
            for (int ks = 0; ks < 2; ++ks)
                qa[rb][ks] = *(short8*)&QtS[(rb * 16 + l16) * 72 + ks * 32 + quad * 8];

        // qpe table via MFMA (M=32, N=64, K=64)
        {
            int mt = wave >> 1;
            int ntA = 2 * (wave & 1), ntB = ntA + 1;
            floatx4 c0f = {0, 0, 0, 0}, c1f = {0, 0, 0, 0};
            for (int ks = 0; ks < 2; ++ks) {
                short8 b0 = *(short8*)&KV[(ntA * 16 + l16) * 72 + ks * 32 + quad * 8];
                short8 b1 = *(short8*)&KV[(ntB * 16 + l16) * 72 + ks * 32 + quad * 8];
                c0f = MFMA16(qa[mt][ks], b0, c0f, 0, 0, 0);
                c1f = MFMA16(qa[mt][ks], b1, c1f, 0, 0, 0);
            }
            for (int r = 0; r < 4; ++r) {
                qpeB[(mt * 16 + quad * 4 + r) * 68 + ntA * 16 + l16] = (short)f2bf(c0f[r]);
                qpeB[(mt * 16 + quad * 4 + r) * 68 + ntB * 16 + l16] = (short)f2bf(c1f[r]);
            }
        }

        const int JT = (i0 + 159) >> 7;
        floatx4 o0 = {0, 0, 0, 0}, o1 = {0, 0, 0, 0};
        const int pv_mt = wave >> 1;
        const int pv_ntA = 2 * (wave & 1), pv_ntB = pv_ntA + 1;
        float l_acc = 0.f;
        float baseAcc = 0.f;

        short8 kreg[4];
        for (int e = 0; e < 4; ++e) {
            int ch = t + 256 * e;
            int jr = ch >> 3, c = ch & 7;
            kreg[e] = *(const short8*)&K[((size_t)(b * Tt + jr)) * Dd + h * DHh + c * 8];
        }

        for (int jt = 0; jt < JT; ++jt) {
            const int j0 = jt * 128;
            __syncthreads();                                    // A: KV free
            for (int e = 0; e < 4; ++e) {
                int ch = t + 256 * e;
                int jr = ch >> 3, c = ch & 7;
                *(short8*)&KV[jr * 72 + c * 8] = kreg[e];
            }
            __syncthreads();                                    // B: K staged
            {
                int ntA = 2 * wave, ntB = ntA + 1;
                floatx4 c00 = {0,0,0,0}, c01 = {0,0,0,0}, c10 = {0,0,0,0}, c11 = {0,0,0,0};
                for (int ks = 0; ks < 2; ++ks) {
                    short8 b0 = *(short8*)&KV[(ntA * 16 + l16) * 72 + ks * 32 + quad * 8];
                    short8 b1 = *(short8*)&KV[(ntB * 16 + l16) * 72 + ks * 32 + quad * 8];
                    c00 = MFMA16(qa[0][ks], b0, c00, 0, 0, 0);
                    c01 = MFMA16(qa[0][ks], b1, c01, 0, 0, 0);
                    c10 = MFMA16(qa[1][ks], b0, c10, 0, 0, 0);
                    c11 = MFMA16(qa[1][ks], b1, c11, 0, 0, 0);
                }
                for (int r = 0; r < 4; ++r) {
                    Sld[(quad * 4 + r) * 132 + ntA * 16 + l16] = c00[r];
                    Sld[(quad * 4 + r) * 132 + ntB * 16 + l16] = c01[r];
                    Sld[(16 + quad * 4 + r) * 132 + ntA * 16 + l16] = c10[r];
                    Sld[(16 + quad * 4 + r) * 132 + ntB * 16 + l16] = c11[r];
                }
            }
            __syncthreads();                                    // C: S ready
            short8 vreg[4];
            for (int e = 0; e < 4; ++e) {
                int ch = t + 256 * e;
                int d = ch >> 4, c = ch & 15;
                vreg[e] = *(const short8*)&Vt[((size_t)(b * Dd + h * DHh + d)) * Tt + j0 + c * 8];
            }
            if (jt + 1 < JT) {
                for (int e = 0; e < 4; ++e) {
                    int ch = t + 256 * e;
                    int jr = ch >> 3, c = ch & 7;
                    kreg[e] = *(const short8*)&K[((size_t)(b * Tt + j0 + 128 + jr)) * Dd + h * DHh + c * 8];
                }
            }
            {
                // read own 16 S floats (short-typed loads, bit-cast: TBAA-safe alias)
                floatx4 qv[4];
                for (int q4 = 0; q4 < 4; ++q4) {
                    short8 qraw = *(short8*)&SldS[sr * 264 + ss * 32 + q4 * 8];
                    __builtin_memcpy(&qv[q4], &qraw, 16);
                }
                float gt[16];
                float gs = 0.f;
                for (int e = 0; e < 16; ++e) {
                    int j = j0 + ss * 16 + e;
                    float qk = qv[e >> 2][e & 3];
                    float g = (j <= irow) ? fsigm(qk * inv_scale) : 0.f;
                    gt[e] = g;
                    gs += g;
                }
                float inc = gs;
                for (int d2 = 1; d2 < 8; d2 <<= 1) {
                    float n = __shfl_up(inc, d2, 64);
                    if ((lane & 7) >= d2) inc += n;
                }
                float base = baseAcc + (inc - gs);
                float run = 0.f;
                short8 p0, p1;
                for (int e = 0; e < 16; ++e) {
                    run += gt[e];
                    int j = j0 + ss * 16 + e;
                    float pos = tot - (base + run);
                    pos = fminf(fmaxf(pos, 0.f), 63.f);
                    float pf = floorf(pos);
                    float al = pos - pf;
                    int fi = (int)pf;
                    int ci = fi + 1; if (ci > 63) ci = 63;
                    float qp = (1.f - al) * bf2fs(qpeB[sr * 68 + fi]) + al * bf2fs(qpeB[sr * 68 + ci]);
                    float qk = qv[e >> 2][e & 3];
                    float p = (j <= irow) ? __expf((qk + qp) * inv_scale) : 0.f;
                    if (e < 8) p0[e] = (short)f2bf(p); else p1[e - 8] = (short)f2bf(p);
                    l_acc += p;
                }
                // P overwrites the low half of this thread's OWN consumed S region
                *(short8*)&SldS[sr * 264 + ss * 32]     = p0;
                *(short8*)&SldS[sr * 264 + ss * 32 + 8] = p1;
                baseAcc += grow[jt];
            }
            for (int e = 0; e < 4; ++e) {
                int ch = t + 256 * e;
                int d = ch >> 4, c = ch & 15;
                *(short8*)&KV[d * 136 + c * 8] = vreg[e];
            }
            __syncthreads();                                    // D: P + V ready
            for (int ks = 0; ks < 4; ++ks) {
                short8 a  = *(short8*)&SldS[(pv_mt * 16 + l16) * 264 + ks * 64
                                            + ((quad >> 1) << 5) + ((quad & 1) << 3)];
                short8 b0 = *(short8*)&KV[(pv_ntA * 16 + l16) * 136 + ks * 32 + quad * 8];
                short8 b1 = *(short8*)&KV[(pv_ntB * 16 + l16) * 136 + ks * 32 + quad * 8];
                o0 = MFMA16(a, b0, o0, 0, 0, 0);
                o1 = MFMA16(a, b1, o1, 0, 0, 0);
            }
        }
        float lr = l_acc;
        for (int d2 = 4; d2 >= 1; d2 >>= 1) lr += __shfl_xor(lr, d2, 64);
        if (ss == 0) lrow[sr] = lr;
        __syncthreads();
        for (int r = 0; r < 4; ++r) {
            int row = pv_mt * 16 + quad * 4 + r;
            float inv = __builtin_amdgcn_rcpf(lrow[row]);
            size_t off = ((size_t)(b * Tt + i0 + row)) * Dd + h * DHh;
            AOb[off + pv_ntA * 16 + l16] = (short)f2bf(o0[r] * inv);
            AOb[off + pv_ntB * 16 + l16] = (short)f2bf(o1[r] * inv);
        }
    }
}

// ---------------- launch ---------------------------------------------------------
extern "C" void kernel_launch(void* const* d_in, const int* in_sizes, int n_in,
                              void* d_out, int out_size, void* d_ws, size_t ws_size,
                              hipStream_t stream)
{
    const float* x  = (const float*)d_in[0];
    const float* Wq = (const float*)d_in[1];
    const float* bq = (const float*)d_in[2];
    const float* Wk = (const float*)d_in[3];
    const float* bk = (const float*)d_in[4];
    const float* Wv = (const float*)d_in[5];
    const float* bv = (const float*)d_in[6];
    const float* Wo = (const float*)d_in[7];
    const float* bo = (const float*)d_in[8];
    const float* pe = (const float*)d_in[9];
    // d_in[10]: causal mask (j > i) — structural, unused

    short* xb   = (short*)d_ws;                         //  4 MB
    short* Wqb  = xb   + (size_t)BTt * Dd;              //  2 MB
    short* Wkb  = Wqb  + (size_t)Dd * Dd;               //  2 MB
    short* Wvb  = Wkb  + (size_t)Dd * Dd;               //  2 MB
    short* Wob  = Wvb  + (size_t)Dd * Dd;               //  2 MB
    short* Qb   = Wob  + (size_t)Dd * Dd;               //  4 MB
    short* Kb   = Qb   + (size_t)BTt * Dd;              //  4 MB
    short* Vrow = Kb   + (size_t)BTt * Dd;              //  4 MB
    short* Vtg  = Vrow + (size_t)BTt * Dd;              //  4 MB
    short* AOb  = Vtg  + (size_t)BTt * Dd;              //  4 MB
    float* gts  = (float*)(AOb + (size_t)BTt * Dd);     //  1 MB

    dim3 gc(BTt * Dd / 8 / 256, 5);
    conv_bf16<<<gc, 256, 0, stream>>>(x, Wq, Wk, Wv, Wo, xb, Wqb, Wkb, Wvb, Wob);

    dim3 gq(BTt / BM, Dd / BN, 3);
    gemm_qkv<<<gq, 256, 0, stream>>>(xb, Wqb, Wkb, Wvb, bq, bk, bv, Qb, Kb, Vrow);

    dim3 gg(272, Hh, 2);    // x<256: gate sums; x>=256: V transpose (y = d-tile)
    vt_gates<<<gg, 256, 0, stream>>>(Qb, Kb, Vrow, Vtg, gts);

    dim3 ga(Tt / 32 / 2, Hh, 2);   // paired i-tiles: block bx does (31-bx) then bx
    cope_attn<<<ga, 256, 0, stream>>>(Qb, Kb, Vtg, pe, gts, AOb);

    dim3 go(BTt / BM, Dd / BN, 1);
    gemm_o<<<go, 256, 0, stream>>>(AOb, Wob, bo, (float*)d_out);
}

// Round 3
// 182.268 us; speedup vs baseline: 1.2089x; 1.1022x over previous
//
#include <hip/hip_runtime.h>
#include <math.h>

#define Tt 1024
#define Dd 1024
#define Hh 16
#define DHh 64
#define MAXPOS 64
#define BTt 2048

typedef short short8 __attribute__((ext_vector_type(8)));
typedef float floatx4 __attribute__((ext_vector_type(4)));

#define MFMA16 __builtin_amdgcn_mfma_f32_16x16x32_bf16

__device__ __forceinline__ unsigned short f2bf(float f) {
    unsigned u;
    __builtin_memcpy(&u, &f, 4);
    u = (u + 0x7FFFu + ((u >> 16) & 1u)) >> 16;
    return (unsigned short)u;
}
__device__ __forceinline__ float bf2fs(short s) {
    unsigned u = ((unsigned)(unsigned short)s) << 16;
    float f;
    __builtin_memcpy(&f, &u, 4);
    return f;
}
// fast sigmoid: v_rcp_f32 instead of IEEE div (~1 ulp; threshold margin is 4x)
__device__ __forceinline__ float fsigm(float x) {
    return __builtin_amdgcn_rcpf(1.f + __expf(-x));
}

// ---------------- fp32 -> bf16 pre-conversion (x + 4 weights) -------------------
__global__ __launch_bounds__(256) void conv_bf16(
    const float* __restrict__ x,  const float* __restrict__ W0,
    const float* __restrict__ W1, const float* __restrict__ W2,
    const float* __restrict__ W3,
    short* __restrict__ xb, short* __restrict__ w0b, short* __restrict__ w1b,
    short* __restrict__ w2b, short* __restrict__ w3b)
{
    const float* src; short* dst; int n;
    switch (blockIdx.y) {
        case 0:  src = x;  dst = xb;  n = BTt * Dd; break;
        case 1:  src = W0; dst = w0b; n = Dd * Dd;  break;
        case 2:  src = W1; dst = w1b; n = Dd * Dd;  break;
        case 3:  src = W2; dst = w2b; n = Dd * Dd;  break;
        default: src = W3; dst = w3b; n = Dd * Dd;  break;
    }
    int idx = (blockIdx.x * 256 + threadIdx.x) * 8;
    if (idx >= n) return;
    floatx4 a0 = *(const floatx4*)&src[idx];
    floatx4 a1 = *(const floatx4*)&src[idx + 4];
    short8 s;
    for (int e = 0; e < 4; ++e) {
        s[e]     = (short)f2bf(a0[e]);
        s[e + 4] = (short)f2bf(a1[e]);
    }
    *(short8*)&dst[idx] = s;
}

// ------------- MFMA GEMM: C = A[M,K] * W[N,K]^T + bias (bf16 in, bf16 MFMA)
// R11-proven staging: padded LDS (stride 72), coalesced short8 loads via VGPR.
#define BM 128
#define BN 128
#define BKK 64
#define LDSS 72

template <int MODE>   // 0: fp32 out, 1: bf16 out
__device__ __forceinline__ void gemm_body(const short* __restrict__ A,
                                          const short* __restrict__ W,
                                          const float* __restrict__ bias,
                                          void* __restrict__ Cout,
                                          int N, int K)
{
    __shared__ __align__(16) short Ash[BM * LDSS];
    __shared__ __align__(16) short Bsh[BN * LDSS];
    const int t = threadIdx.x;
    const int lane = t & 63, wave = t >> 6;
    const int wm = wave >> 1, wn = wave & 1;
    const int quad = lane >> 4, l16 = lane & 15;
    const int row0 = blockIdx.x * BM, col0 = blockIdx.y * BN;

    floatx4 acc[4][4];
    for (int a = 0; a < 4; ++a)
        for (int b2 = 0; b2 < 4; ++b2)
            acc[a][b2] = (floatx4){0.f, 0.f, 0.f, 0.f};

    for (int kb = 0; kb < K; kb += BKK) {
        __syncthreads();
        for (int q2 = 0; q2 < 4; ++q2) {
            int ch = t + 256 * q2;
            int r = ch >> 3, c = ch & 7;
            *(short8*)&Ash[r * LDSS + c * 8] =
                *(const short8*)&A[(size_t)(row0 + r) * K + kb + c * 8];
            *(short8*)&Bsh[r * LDSS + c * 8] =
                *(const short8*)&W[(size_t)(col0 + r) * K + kb + c * 8];
        }
        __syncthreads();
        for (int ks = 0; ks < BKK / 32; ++ks) {
            short8 af[4], bfr[4];
            for (int tm = 0; tm < 4; ++tm)
                af[tm] = *(short8*)&Ash[(wm * 64 + tm * 16 + l16) * LDSS + ks * 32 + quad * 8];
            for (int tn = 0; tn < 4; ++tn)
                bfr[tn] = *(short8*)&Bsh[(wn * 64 + tn * 16 + l16) * LDSS + ks * 32 + quad * 8];
            for (int tm = 0; tm < 4; ++tm)
                for (int tn = 0; tn < 4; ++tn)
                    acc[tm][tn] = MFMA16(af[tm], bfr[tn], acc[tm][tn], 0, 0, 0);
        }
    }
    for (int tm = 0; tm < 4; ++tm)
        for (int tn = 0; tn < 4; ++tn) {
            int col = col0 + wn * 64 + tn * 16 + l16;
            float bv = bias[col];
            for (int r = 0; r < 4; ++r) {
                int row = row0 + wm * 64 + tm * 16 + quad * 4 + r;
                float v = acc[tm][tn][r] + bv;
                if (MODE == 0) ((float*)Cout)[(size_t)row * N + col] = v;
                else           ((short*)Cout)[(size_t)row * N + col] = (short)f2bf(v);
            }
        }
}

__global__ __launch_bounds__(256) void gemm_qkv(
    const short* __restrict__ xb,
    const short* __restrict__ Wqb, const short* __restrict__ Wkb,
    const short* __restrict__ Wvb,
    const float* __restrict__ bq, const float* __restrict__ bk,
    const float* __restrict__ bv,
    short* __restrict__ Qb, short* __restrict__ Kb, short* __restrict__ Vrow)
{
    if (blockIdx.z == 0)      gemm_body<1>(xb, Wqb, bq, Qb, Dd, Dd);
    else if (blockIdx.z == 1) gemm_body<1>(xb, Wkb, bk, Kb, Dd, Dd);
    else                      gemm_body<1>(xb, Wvb, bv, Vrow, Dd, Dd);
}

__global__ __launch_bounds__(256) void gemm_o(
    const short* __restrict__ A, const short* __restrict__ W,
    const float* __restrict__ bias, float* __restrict__ C)
{
    gemm_body<0>(A, W, bias, C, Dd, Dd);
}

// ---------------- V transpose: Vt[b][d][j] = Vrow[b][j][d], 64x64 tiles ---------
// (R14: gate-sum pre-pass eliminated -- cope_attn now computes the gate suffix
//  on the fly by sweeping j-tiles from the diagonal backwards. This kernel is
//  all that remains of the old vt_gates.)
__global__ __launch_bounds__(256) void v_transpose(
    const short* __restrict__ Vrow, short* __restrict__ Vt)
{
    __shared__ __align__(16) short L[64 * 72];
    const int t = threadIdx.x;
    const int j0 = blockIdx.x * 64, d0 = blockIdx.y * 64, b = blockIdx.z;
    for (int s = 0; s < 2; ++s) {
        int c = t * 2 + s;
        int jr = c >> 3, c8 = c & 7;
        *(short8*)&L[jr * 72 + c8 * 8] =
            *(const short8*)&Vrow[((size_t)(b * Tt + j0 + jr)) * Dd + d0 + c8 * 8];
    }
    __syncthreads();
    for (int s = 0; s < 2; ++s) {
        int c = t * 2 + s;
        int dr = c >> 3, c8 = c & 7;
        short8 v;
        for (int e = 0; e < 8; ++e) v[e] = L[(c8 * 8 + e) * 72 + dr];
        *(short8*)&Vt[((size_t)(b * Dd + d0 + dr)) * Tt + j0 + c8 * 8] = v;
    }
}

// ---------------- fused attn: scores + no-max softmax + PV (single pass) --------
// R14: REVERSE j-sweep. pos_j = sum_{k>j} g_k is a suffix sum, so iterating
// j-tiles from the diagonal down to 0 lets a running rightAcc replace the old
// precomputed per-tile gate sums (gts) entirely: no gate pre-pass kernel, no
// gts traffic, identical g values. Within a tile the old prefix shfl_up scan
// becomes a suffix shfl_down scan + a broadcast of the tile-row total.
// R13 pairing kept: block bx does i-tile (31-bx) then bx (9 j-tiles/block).
__global__ __launch_bounds__(256) void cope_attn(
    const short* __restrict__ Q, const short* __restrict__ K,
    const short* __restrict__ Vt, const float* __restrict__ PE,
    short* __restrict__ AOb)
{
    const int h = blockIdx.y, b = blockIdx.z;
    const int t = threadIdx.x, lane = t & 63, wave = t >> 6;
    const int quad = lane >> 4, l16 = lane & 15;

    // SldS: setup Q tile (short) / S tile (f32, row stride 132 floats) /
    //       P tile (bf16, packed, aliased) -- 16.9 KB
    __shared__ __align__(16) short SldS[32 * 264];
    __shared__ __align__(16) short KV[128 * 72];    // PE / K[128][72] / V[64][136]
    __shared__ short qpeB[32 * 68];
    __shared__ float lrow[32];
    float* Sld = (float*)SldS;

    const float inv_scale = 0.125f;
    const int sr = t >> 3, ss = t & 7;

    for (int phase = 0; phase < 2; ++phase) {
        const int it = (phase == 0) ? (31 - (int)blockIdx.x) : (int)blockIdx.x;
        const int i0 = it * 32;
        const int irow = i0 + sr;

        short* QtS = SldS;
        {
            int r = t >> 3, c = t & 7;
            *(short8*)&QtS[r * 72 + c * 8] =
                *(const short8*)&Q[((size_t)(b * Tt + i0 + r)) * Dd + h * DHh + c * 8];
        }
        for (int e = 0; e < 16; ++e) {
            int idx = t + 256 * e;
            int p = idx >> 6, d = idx & 63;
            KV[p * 72 + d] = (short)f2bf(PE[((size_t)h * MAXPOS + p) * DHh + d]);
        }
        __syncthreads();

        short8 qa[2][2];
        for (int rb = 0; rb < 2; ++rb)
            for (int ks = 0; ks < 2; ++ks)
                qa[rb][ks] = *(short8*)&QtS[(rb * 16 + l16) * 72 + ks * 32 + quad * 8];

        // qpe table via MFMA (M=32, N=64, K=64)
        {
            int mt = wave >> 1;
            int ntA = 2 * (wave & 1), ntB = ntA + 1;
            floatx4 c0f = {0, 0, 0, 0}, c1f = {0, 0, 0, 0};
            for (int ks = 0; ks < 2; ++ks) {
                short8 b0 = *(short8*)&KV[(ntA * 16 + l16) * 72 + ks * 32 + quad * 8];
                short8 b1 = *(short8*)&KV[(ntB * 16 + l16) * 72 + ks * 32 + quad * 8];
                c0f = MFMA16(qa[mt][ks], b0, c0f, 0, 0, 0);
                c1f = MFMA16(qa[mt][ks], b1, c1f, 0, 0, 0);
            }
            for (int r = 0; r < 4; ++r) {
                qpeB[(mt * 16 + quad * 4 + r) * 68 + ntA * 16 + l16] = (short)f2bf(c0f[r]);
                qpeB[(mt * 16 + quad * 4 + r) * 68 + ntB * 16 + l16] = (short)f2bf(c1f[r]);
            }
        }

        const int JT = (i0 + 159) >> 7;
        floatx4 o0 = {0, 0, 0, 0}, o1 = {0, 0, 0, 0};
        const int pv_mt = wave >> 1;
        const int pv_ntA = 2 * (wave & 1), pv_ntB = pv_ntA + 1;
        float l_acc = 0.f;
        float rightAcc = 0.f;     // sum of gates in tiles already processed (k > current tile)

        short8 kreg[4];
        for (int e = 0; e < 4; ++e) {
            int ch = t + 256 * e;
            int jr = ch >> 3, c = ch & 7;
            kreg[e] = *(const short8*)&K[((size_t)(b * Tt + (JT - 1) * 128 + jr)) * Dd + h * DHh + c * 8];
        }

        for (int jt = JT - 1; jt >= 0; --jt) {
            const int j0 = jt * 128;
            __syncthreads();                                    // A: KV free
            for (int e = 0; e < 4; ++e) {
                int ch = t + 256 * e;
                int jr = ch >> 3, c = ch & 7;
                *(short8*)&KV[jr * 72 + c * 8] = kreg[e];
            }
            __syncthreads();                                    // B: K staged
            {
                int ntA = 2 * wave, ntB = ntA + 1;
                floatx4 c00 = {0,0,0,0}, c01 = {0,0,0,0}, c10 = {0,0,0,0}, c11 = {0,0,0,0};
                for (int ks = 0; ks < 2; ++ks) {
                    short8 b0 = *(short8*)&KV[(ntA * 16 + l16) * 72 + ks * 32 + quad * 8];
                    short8 b1 = *(short8*)&KV[(ntB * 16 + l16) * 72 + ks * 32 + quad * 8];
                    c00 = MFMA16(qa[0][ks], b0, c00, 0, 0, 0);
                    c01 = MFMA16(qa[0][ks], b1, c01, 0, 0, 0);
                    c10 = MFMA16(qa[1][ks], b0, c10, 0, 0, 0);
                    c11 = MFMA16(qa[1][ks], b1, c11, 0, 0, 0);
                }
                for (int r = 0; r < 4; ++r) {
                    Sld[(quad * 4 + r) * 132 + ntA * 16 + l16] = c00[r];
                    Sld[(quad * 4 + r) * 132 + ntB * 16 + l16] = c01[r];
                    Sld[(16 + quad * 4 + r) * 132 + ntA * 16 + l16] = c10[r];
                    Sld[(16 + quad * 4 + r) * 132 + ntB * 16 + l16] = c11[r];
                }
            }
            __syncthreads();                                    // C: S ready
            short8 vreg[4];
            for (int e = 0; e < 4; ++e) {
                int ch = t + 256 * e;
                int d = ch >> 4, c = ch & 15;
                vreg[e] = *(const short8*)&Vt[((size_t)(b * Dd + h * DHh + d)) * Tt + j0 + c * 8];
            }
            if (jt > 0) {
                for (int e = 0; e < 4; ++e) {
                    int ch = t + 256 * e;
                    int jr = ch >> 3, c = ch & 7;
                    kreg[e] = *(const short8*)&K[((size_t)(b * Tt + j0 - 128 + jr)) * Dd + h * DHh + c * 8];
                }
            }
            {
                // read own 16 S floats (short-typed loads, bit-cast: TBAA-safe alias)
                floatx4 qv[4];
                for (int q4 = 0; q4 < 4; ++q4) {
                    short8 qraw = *(short8*)&SldS[sr * 264 + ss * 32 + q4 * 8];
                    __builtin_memcpy(&qv[q4], &qraw, 16);
                }
                float gt[16];
                float gs = 0.f;
                for (int e = 0; e < 16; ++e) {
                    int j = j0 + ss * 16 + e;
                    float qk = qv[e >> 2][e & 3];
                    float g = (j <= irow) ? fsigm(qk * inv_scale) : 0.f;
                    gt[e] = g;
                    gs += g;
                }
                // inclusive suffix-scan of group sums across the 8 ss-groups
                float inc = gs;
                for (int d2 = 1; d2 < 8; d2 <<= 1) {
                    float n = __shfl_down(inc, d2, 64);
                    if ((lane & 7) + d2 < 8) inc += n;
                }
                // tile-row total lives at ss=0; broadcast within the row group
                float tileTot = __shfl(inc, lane & 56, 64);
                float base = rightAcc + (inc - gs);   // gates strictly right of this group
                float run = 0.f;                      // suffix within group (exclusive)
                short8 p0, p1;
                for (int e = 15; e >= 0; --e) {
                    int j = j0 + ss * 16 + e;
                    float pos = base + run;           // = sum_{k > j} g_k
                    run += gt[e];
                    pos = fminf(fmaxf(pos, 0.f), 63.f);
                    float pf = floorf(pos);
                    float al = pos - pf;
                    int fi = (int)pf;
                    int ci = fi + 1; if (ci > 63) ci = 63;
                    float qp = (1.f - al) * bf2fs(qpeB[sr * 68 + fi]) + al * bf2fs(qpeB[sr * 68 + ci]);
                    float qk = qv[e >> 2][e & 3];
                    float p = (j <= irow) ? __expf((qk + qp) * inv_scale) : 0.f;
                    if (e < 8) p0[e] = (short)f2bf(p); else p1[e - 8] = (short)f2bf(p);
                    l_acc += p;
                }
                // P overwrites the low half of this thread's OWN consumed S region
                *(short8*)&SldS[sr * 264 + ss * 32]     = p0;
                *(short8*)&SldS[sr * 264 + ss * 32 + 8] = p1;
                rightAcc += tileTot;
            }
            for (int e = 0; e < 4; ++e) {
                int ch = t + 256 * e;
                int d = ch >> 4, c = ch & 15;
                *(short8*)&KV[d * 136 + c * 8] = vreg[e];
            }
            __syncthreads();                                    // D: P + V ready
            for (int ks = 0; ks < 4; ++ks) {
                short8 a  = *(short8*)&SldS[(pv_mt * 16 + l16) * 264 + ks * 64
                                            + ((quad >> 1) << 5) + ((quad & 1) << 3)];
                short8 b0 = *(short8*)&KV[(pv_ntA * 16 + l16) * 136 + ks * 32 + quad * 8];
                short8 b1 = *(short8*)&KV[(pv_ntB * 16 + l16) * 136 + ks * 32 + quad * 8];
                o0 = MFMA16(a, b0, o0, 0, 0, 0);
                o1 = MFMA16(a, b1, o1, 0, 0, 0);
            }
        }
        float lr = l_acc;
        for (int d2 = 4; d2 >= 1; d2 >>= 1) lr += __shfl_xor(lr, d2, 64);
        if (ss == 0) lrow[sr] = lr;
        __syncthreads();
        for (int r = 0; r < 4; ++r) {
            int row = pv_mt * 16 + quad * 4 + r;
            float inv = __builtin_amdgcn_rcpf(lrow[row]);
            size_t off = ((size_t)(b * Tt + i0 + row)) * Dd + h * DHh;
            AOb[off + pv_ntA * 16 + l16] = (short)f2bf(o0[r] * inv);
            AOb[off + pv_ntB * 16 + l16] = (short)f2bf(o1[r] * inv);
        }
    }
}

// ---------------- launch ---------------------------------------------------------
extern "C" void kernel_launch(void* const* d_in, const int* in_sizes, int n_in,
                              void* d_out, int out_size, void* d_ws, size_t ws_size,
                              hipStream_t stream)
{
    const float* x  = (const float*)d_in[0];
    const float* Wq = (const float*)d_in[1];
    const float* bq = (const float*)d_in[2];
    const float* Wk = (const float*)d_in[3];
    const float* bk = (const float*)d_in[4];
    const float* Wv = (const float*)d_in[5];
    const float* bv = (const float*)d_in[6];
    const float* Wo = (const float*)d_in[7];
    const float* bo = (const float*)d_in[8];
    const float* pe = (const float*)d_in[9];
    // d_in[10]: causal mask (j > i) — structural, unused

    short* xb   = (short*)d_ws;                         //  4 MB
    short* Wqb  = xb   + (size_t)BTt * Dd;              //  2 MB
    short* Wkb  = Wqb  + (size_t)Dd * Dd;               //  2 MB
    short* Wvb  = Wkb  + (size_t)Dd * Dd;               //  2 MB
    short* Wob  = Wvb  + (size_t)Dd * Dd;               //  2 MB
    short* Qb   = Wob  + (size_t)Dd * Dd;               //  4 MB
    short* Kb   = Qb   + (size_t)BTt * Dd;              //  4 MB
    short* Vrow = Kb   + (size_t)BTt * Dd;              //  4 MB
    short* Vtg  = Vrow + (size_t)BTt * Dd;              //  4 MB
    short* AOb  = Vtg  + (size_t)BTt * Dd;              //  4 MB

    dim3 gc(BTt * Dd / 8 / 256, 5);
    conv_bf16<<<gc, 256, 0, stream>>>(x, Wq, Wk, Wv, Wo, xb, Wqb, Wkb, Wvb, Wob);

    dim3 gq(BTt / BM, Dd / BN, 3);
    gemm_qkv<<<gq, 256, 0, stream>>>(xb, Wqb, Wkb, Wvb, bq, bk, bv, Qb, Kb, Vrow);

    dim3 gv(Tt / 64, Dd / 64, 2);
    v_transpose<<<gv, 256, 0, stream>>>(Vrow, Vtg);

    dim3 ga(Tt / 32 / 2, Hh, 2);   // paired i-tiles: block bx does (31-bx) then bx
    cope_attn<<<ga, 256, 0, stream>>>(Qb, Kb, Vtg, pe, AOb);

    dim3 go(BTt / BM, Dd / BN, 1);
    gemm_o<<<go, 256, 0, stream>>>(AOb, Wob, bo, (float*)d_out);
}

// Round 4
// 180.979 us; speedup vs baseline: 1.2175x; 1.0071x over previous
//
#include <hip/hip_runtime.h>
#include <math.h>

#define Tt 1024
#define Dd 1024
#define Hh 16
#define DHh 64
#define MAXPOS 64
#define BTt 2048

typedef short short8 __attribute__((ext_vector_type(8)));
typedef float floatx4 __attribute__((ext_vector_type(4)));

#define MFMA16 __builtin_amdgcn_mfma_f32_16x16x32_bf16

__device__ __forceinline__ unsigned short f2bf(float f) {
    unsigned u;
    __builtin_memcpy(&u, &f, 4);
    u = (u + 0x7FFFu + ((u >> 16) & 1u)) >> 16;
    return (unsigned short)u;
}
__device__ __forceinline__ float bf2fs(short s) {
    unsigned u = ((unsigned)(unsigned short)s) << 16;
    float f;
    __builtin_memcpy(&f, &u, 4);
    return f;
}
// fast sigmoid: v_rcp_f32 instead of IEEE div (~1 ulp; threshold margin is 4x)
__device__ __forceinline__ float fsigm(float x) {
    return __builtin_amdgcn_rcpf(1.f + __expf(-x));
}
// async global->LDS DMA, 16B/lane. LDS dest is wave-uniform base + lane*16;
// global src is per-lane. (m97 staging pattern; compiler never auto-emits this.)
__device__ __forceinline__ void gl2lds16(const short* __restrict__ g, short* l) {
    __builtin_amdgcn_global_load_lds(
        (const __attribute__((address_space(1))) void*)g,
        (__attribute__((address_space(3))) void*)l,
        16, 0, 0);
}

// ---------------- fp32 -> bf16 pre-conversion (x + 4 weights) -------------------
__global__ __launch_bounds__(256) void conv_bf16(
    const float* __restrict__ x,  const float* __restrict__ W0,
    const float* __restrict__ W1, const float* __restrict__ W2,
    const float* __restrict__ W3,
    short* __restrict__ xb, short* __restrict__ w0b, short* __restrict__ w1b,
    short* __restrict__ w2b, short* __restrict__ w3b)
{
    const float* src; short* dst; int n;
    switch (blockIdx.y) {
        case 0:  src = x;  dst = xb;  n = BTt * Dd; break;
        case 1:  src = W0; dst = w0b; n = Dd * Dd;  break;
        case 2:  src = W1; dst = w1b; n = Dd * Dd;  break;
        case 3:  src = W2; dst = w2b; n = Dd * Dd;  break;
        default: src = W3; dst = w3b; n = Dd * Dd;  break;
    }
    int idx = (blockIdx.x * 256 + threadIdx.x) * 8;
    if (idx >= n) return;
    floatx4 a0 = *(const floatx4*)&src[idx];
    floatx4 a1 = *(const floatx4*)&src[idx + 4];
    short8 s;
    for (int e = 0; e < 4; ++e) {
        s[e]     = (short)f2bf(a0[e]);
        s[e + 4] = (short)f2bf(a1[e]);
    }
    *(short8*)&dst[idx] = s;
}

// ------------- MFMA GEMM: C = A[M,K] * W[N,K]^T + bias (bf16 in, bf16 MFMA)
// R15: m97-style staging. global_load_lds dwordx4 into LINEAR LDS (stride 64
// shorts -- DMA dest must be contiguous, no padding). Tile 128x64, 4 waves of
// 32x64 (acc[2][4]): qkv grid 384->768 blocks (3/CU), gemm_o 128->256 blocks
// (was 0.5/CU -- half the chip idle). 16-way ds_read bank conflict of linear
// LDS accepted per T2 regime-gate (null at 2-phase; staging dominates).
template <int MODE>   // 0: fp32 out, 1: bf16 out
__device__ __forceinline__ void gemm_body(const short* __restrict__ A,
                                          const short* __restrict__ W,
                                          const float* __restrict__ bias,
                                          void* __restrict__ Cout,
                                          int N, int K)
{
    __shared__ __align__(16) short Ash[128 * 64];
    __shared__ __align__(16) short Bsh[64 * 64];
    const int t = threadIdx.x;
    const int lane = t & 63, wave = t >> 6;
    const int quad = lane >> 4, l16 = lane & 15;
    const int row0 = blockIdx.x * 128, col0 = blockIdx.y * 64;

    // per-lane source coords within an 8-row DMA stripe
    const int g_r = lane >> 3, g_c = (lane & 7) * 8;

    floatx4 acc[2][4];
    for (int a = 0; a < 2; ++a)
        for (int b2 = 0; b2 < 4; ++b2)
            acc[a][b2] = (floatx4){0.f, 0.f, 0.f, 0.f};

    for (int kb = 0; kb < K; kb += 64) {
        if (kb) __syncthreads();            // prev compute done before overwrite
        for (int i = 0; i < 4; ++i) {       // A: 128 rows, 8-row stripe per instr
            int rbase = (wave * 4 + i) * 8;
            gl2lds16(&A[(size_t)(row0 + rbase + g_r) * K + kb + g_c],
                     &Ash[rbase * 64]);
        }
        for (int i = 0; i < 2; ++i) {       // B: 64 rows
            int rbase = (wave * 2 + i) * 8;
            gl2lds16(&W[(size_t)(col0 + rbase + g_r) * K + kb + g_c],
                     &Bsh[rbase * 64]);
        }
        __syncthreads();                    // barrier drains vmcnt -> LDS ready
        for (int ks = 0; ks < 2; ++ks) {
            short8 af[2], bfr[4];
            for (int tm = 0; tm < 2; ++tm)
                af[tm] = *(short8*)&Ash[(wave * 32 + tm * 16 + l16) * 64 + ks * 32 + quad * 8];
            for (int tn = 0; tn < 4; ++tn)
                bfr[tn] = *(short8*)&Bsh[(tn * 16 + l16) * 64 + ks * 32 + quad * 8];
            for (int tm = 0; tm < 2; ++tm)
                for (int tn = 0; tn < 4; ++tn)
                    acc[tm][tn] = MFMA16(af[tm], bfr[tn], acc[tm][tn], 0, 0, 0);
        }
    }
    for (int tm = 0; tm < 2; ++tm)
        for (int tn = 0; tn < 4; ++tn) {
            int col = col0 + tn * 16 + l16;
            float bv = bias[col];
            for (int r = 0; r < 4; ++r) {
                int row = row0 + wave * 32 + tm * 16 + quad * 4 + r;
                float v = acc[tm][tn][r] + bv;
                if (MODE == 0) ((float*)Cout)[(size_t)row * N + col] = v;
                else           ((short*)Cout)[(size_t)row * N + col] = (short)f2bf(v);
            }
        }
}

__global__ __launch_bounds__(256) void gemm_qkv(
    const short* __restrict__ xb,
    const short* __restrict__ Wqb, const short* __restrict__ Wkb,
    const short* __restrict__ Wvb,
    const float* __restrict__ bq, const float* __restrict__ bk,
    const float* __restrict__ bv,
    short* __restrict__ Qb, short* __restrict__ Kb, short* __restrict__ Vrow)
{
    if (blockIdx.z == 0)      gemm_body<1>(xb, Wqb, bq, Qb, Dd, Dd);
    else if (blockIdx.z == 1) gemm_body<1>(xb, Wkb, bk, Kb, Dd, Dd);
    else                      gemm_body<1>(xb, Wvb, bv, Vrow, Dd, Dd);
}

__global__ __launch_bounds__(256) void gemm_o(
    const short* __restrict__ A, const short* __restrict__ W,
    const float* __restrict__ bias, float* __restrict__ C)
{
    gemm_body<0>(A, W, bias, C, Dd, Dd);
}

// ---------------- V transpose: Vt[b][d][j] = Vrow[b][j][d], 64x64 tiles ---------
__global__ __launch_bounds__(256) void v_transpose(
    const short* __restrict__ Vrow, short* __restrict__ Vt)
{
    __shared__ __align__(16) short L[64 * 72];
    const int t = threadIdx.x;
    const int j0 = blockIdx.x * 64, d0 = blockIdx.y * 64, b = blockIdx.z;
    for (int s = 0; s < 2; ++s) {
        int c = t * 2 + s;
        int jr = c >> 3, c8 = c & 7;
        *(short8*)&L[jr * 72 + c8 * 8] =
            *(const short8*)&Vrow[((size_t)(b * Tt + j0 + jr)) * Dd + d0 + c8 * 8];
    }
    __syncthreads();
    for (int s = 0; s < 2; ++s) {
        int c = t * 2 + s;
        int dr = c >> 3, c8 = c & 7;
        short8 v;
        for (int e = 0; e < 8; ++e) v[e] = L[(c8 * 8 + e) * 72 + dr];
        *(short8*)&Vt[((size_t)(b * Dd + d0 + dr)) * Tt + j0 + c8 * 8] = v;
    }
}

// ---------------- fused attn: scores + no-max softmax + PV (single pass) --------
// R14: REVERSE j-sweep (suffix gate sums on the fly, no pre-pass).
// R13 pairing: block bx does i-tile (31-bx) then bx (9 j-tiles/block).
__global__ __launch_bounds__(256) void cope_attn(
    const short* __restrict__ Q, const short* __restrict__ K,
    const short* __restrict__ Vt, const float* __restrict__ PE,
    short* __restrict__ AOb)
{
    const int h = blockIdx.y, b = blockIdx.z;
    const int t = threadIdx.x, lane = t & 63, wave = t >> 6;
    const int quad = lane >> 4, l16 = lane & 15;

    // SldS: setup Q tile (short) / S tile (f32, row stride 132 floats) /
    //       P tile (bf16, packed, aliased) -- 16.9 KB
    __shared__ __align__(16) short SldS[32 * 264];
    __shared__ __align__(16) short KV[128 * 72];    // PE / K[128][72] / V[64][136]
    __shared__ short qpeB[32 * 68];
    __shared__ float lrow[32];
    float* Sld = (float*)SldS;

    const float inv_scale = 0.125f;
    const int sr = t >> 3, ss = t & 7;

    for (int phase = 0; phase < 2; ++phase) {
        const int it = (phase == 0) ? (31 - (int)blockIdx.x) : (int)blockIdx.x;
        const int i0 = it * 32;
        const int irow = i0 + sr;

        short* QtS = SldS;
        {
            int r = t >> 3, c = t & 7;
            *(short8*)&QtS[r * 72 + c * 8] =
                *(const short8*)&Q[((size_t)(b * Tt + i0 + r)) * Dd + h * DHh + c * 8];
        }
        for (int e = 0; e < 16; ++e) {
            int idx = t + 256 * e;
            int p = idx >> 6, d = idx & 63;
            KV[p * 72 + d] = (short)f2bf(PE[((size_t)h * MAXPOS + p) * DHh + d]);
        }
        __syncthreads();

        short8 qa[2][2];
        for (int rb = 0; rb < 2; ++rb)
            for (int ks = 0; ks < 2; ++ks)
                qa[rb][ks] = *(short8*)&QtS[(rb * 16 + l16) * 72 + ks * 32 + quad * 8];

        // qpe table via MFMA (M=32, N=64, K=64)
        {
            int mt = wave >> 1;
            int ntA = 2 * (wave & 1), ntB = ntA + 1;
            floatx4 c0f = {0, 0, 0, 0}, c1f = {0, 0, 0, 0};
            for (int ks = 0; ks < 2; ++ks) {
                short8 b0 = *(short8*)&KV[(ntA * 16 + l16) * 72 + ks * 32 + quad * 8];
                short8 b1 = *(short8*)&KV[(ntB * 16 + l16) * 72 + ks * 32 + quad * 8];
                c0f = MFMA16(qa[mt][ks], b0, c0f, 0, 0, 0);
                c1f = MFMA16(qa[mt][ks], b1, c1f, 0, 0, 0);
            }
            for (int r = 0; r < 4; ++r) {
                qpeB[(mt * 16 + quad * 4 + r) * 68 + ntA * 16 + l16] = (short)f2bf(c0f[r]);
                qpeB[(mt * 16 + quad * 4 + r) * 68 + ntB * 16 + l16] = (short)f2bf(c1f[r]);
            }
        }

        const int JT = (i0 + 159) >> 7;
        floatx4 o0 = {0, 0, 0, 0}, o1 = {0, 0, 0, 0};
        const int pv_mt = wave >> 1;
        const int pv_ntA = 2 * (wave & 1), pv_ntB = pv_ntA + 1;
        float l_acc = 0.f;
        float rightAcc = 0.f;     // sum of gates in tiles already processed (k > current tile)

        short8 kreg[4];
        for (int e = 0; e < 4; ++e) {
            int ch = t + 256 * e;
            int jr = ch >> 3, c = ch & 7;
            kreg[e] = *(const short8*)&K[((size_t)(b * Tt + (JT - 1) * 128 + jr)) * Dd + h * DHh + c * 8];
        }

        for (int jt = JT - 1; jt >= 0; --jt) {
            const int j0 = jt * 128;
            __syncthreads();                                    // A: KV free
            for (int e = 0; e < 4; ++e) {
                int ch = t + 256 * e;
                int jr = ch >> 3, c = ch & 7;
                *(short8*)&KV[jr * 72 + c * 8] = kreg[e];
            }
            __syncthreads();                                    // B: K staged
            {
                int ntA = 2 * wave, ntB = ntA + 1;
                floatx4 c00 = {0,0,0,0}, c01 = {0,0,0,0}, c10 = {0,0,0,0}, c11 = {0,0,0,0};
                for (int ks = 0; ks < 2; ++ks) {
                    short8 b0 = *(short8*)&KV[(ntA * 16 + l16) * 72 + ks * 32 + quad * 8];
                    short8 b1 = *(short8*)&KV[(ntB * 16 + l16) * 72 + ks * 32 + quad * 8];
                    c00 = MFMA16(qa[0][ks], b0, c00, 0, 0, 0);
                    c01 = MFMA16(qa[0][ks], b1, c01, 0, 0, 0);
                    c10 = MFMA16(qa[1][ks], b0, c10, 0, 0, 0);
                    c11 = MFMA16(qa[1][ks], b1, c11, 0, 0, 0);
                }
                for (int r = 0; r < 4; ++r) {
                    Sld[(quad * 4 + r) * 132 + ntA * 16 + l16] = c00[r];
                    Sld[(quad * 4 + r) * 132 + ntB * 16 + l16] = c01[r];
                    Sld[(16 + quad * 4 + r) * 132 + ntA * 16 + l16] = c10[r];
                    Sld[(16 + quad * 4 + r) * 132 + ntB * 16 + l16] = c11[r];
                }
            }
            __syncthreads();                                    // C: S ready
            short8 vreg[4];
            for (int e = 0; e < 4; ++e) {
                int ch = t + 256 * e;
                int d = ch >> 4, c = ch & 15;
                vreg[e] = *(const short8*)&Vt[((size_t)(b * Dd + h * DHh + d)) * Tt + j0 + c * 8];
            }
            if (jt > 0) {
                for (int e = 0; e < 4; ++e) {
                    int ch = t + 256 * e;
                    int jr = ch >> 3, c = ch & 7;
                    kreg[e] = *(const short8*)&K[((size_t)(b * Tt + j0 - 128 + jr)) * Dd + h * DHh + c * 8];
                }
            }
            {
                // read own 16 S floats (short-typed loads, bit-cast: TBAA-safe alias)
                floatx4 qv[4];
                for (int q4 = 0; q4 < 4; ++q4) {
                    short8 qraw = *(short8*)&SldS[sr * 264 + ss * 32 + q4 * 8];
                    __builtin_memcpy(&qv[q4], &qraw, 16);
                }
                float gt[16];
                float gs = 0.f;
                for (int e = 0; e < 16; ++e) {
                    int j = j0 + ss * 16 + e;
                    float qk = qv[e >> 2][e & 3];
                    float g = (j <= irow) ? fsigm(qk * inv_scale) : 0.f;
                    gt[e] = g;
                    gs += g;
                }
                // inclusive suffix-scan of group sums across the 8 ss-groups
                float inc = gs;
                for (int d2 = 1; d2 < 8; d2 <<= 1) {
                    float n = __shfl_down(inc, d2, 64);
                    if ((lane & 7) + d2 < 8) inc += n;
                }
                // tile-row total lives at ss=0; broadcast within the row group
                float tileTot = __shfl(inc, lane & 56, 64);
                float base = rightAcc + (inc - gs);   // gates strictly right of this group
                float run = 0.f;                      // suffix within group (exclusive)
                short8 p0, p1;
                for (int e = 15; e >= 0; --e) {
                    int j = j0 + ss * 16 + e;
                    float pos = base + run;           // = sum_{k > j} g_k
                    run += gt[e];
                    pos = fminf(fmaxf(pos, 0.f), 63.f);
                    float pf = floorf(pos);
                    float al = pos - pf;
                    int fi = (int)pf;
                    int ci = fi + 1; if (ci > 63) ci = 63;
                    float qp = (1.f - al) * bf2fs(qpeB[sr * 68 + fi]) + al * bf2fs(qpeB[sr * 68 + ci]);
                    float qk = qv[e >> 2][e & 3];
                    float p = (j <= irow) ? __expf((qk + qp) * inv_scale) : 0.f;
                    if (e < 8) p0[e] = (short)f2bf(p); else p1[e - 8] = (short)f2bf(p);
                    l_acc += p;
                }
                // P overwrites the low half of this thread's OWN consumed S region
                *(short8*)&SldS[sr * 264 + ss * 32]     = p0;
                *(short8*)&SldS[sr * 264 + ss * 32 + 8] = p1;
                rightAcc += tileTot;
            }
            for (int e = 0; e < 4; ++e) {
                int ch = t + 256 * e;
                int d = ch >> 4, c = ch & 15;
                *(short8*)&KV[d * 136 + c * 8] = vreg[e];
            }
            __syncthreads();                                    // D: P + V ready
            for (int ks = 0; ks < 4; ++ks) {
                short8 a  = *(short8*)&SldS[(pv_mt * 16 + l16) * 264 + ks * 64
                                            + ((quad >> 1) << 5) + ((quad & 1) << 3)];
                short8 b0 = *(short8*)&KV[(pv_ntA * 16 + l16) * 136 + ks * 32 + quad * 8];
                short8 b1 = *(short8*)&KV[(pv_ntB * 16 + l16) * 136 + ks * 32 + quad * 8];
                o0 = MFMA16(a, b0, o0, 0, 0, 0);
                o1 = MFMA16(a, b1, o1, 0, 0, 0);
            }
        }
        float lr = l_acc;
        for (int d2 = 4; d2 >= 1; d2 >>= 1) lr += __shfl_xor(lr, d2, 64);
        if (ss == 0) lrow[sr] = lr;
        __syncthreads();
        for (int r = 0; r < 4; ++r) {
            int row = pv_mt * 16 + quad * 4 + r;
            float inv = __builtin_amdgcn_rcpf(lrow[row]);
            size_t off = ((size_t)(b * Tt + i0 + row)) * Dd + h * DHh;
            AOb[off + pv_ntA * 16 + l16] = (short)f2bf(o0[r] * inv);
            AOb[off + pv_ntB * 16 + l16] = (short)f2bf(o1[r] * inv);
        }
    }
}

// ---------------- launch ---------------------------------------------------------
extern "C" void kernel_launch(void* const* d_in, const int* in_sizes, int n_in,
                              void* d_out, int out_size, void* d_ws, size_t ws_size,
                              hipStream_t stream)
{
    const float* x  = (const float*)d_in[0];
    const float* Wq = (const float*)d_in[1];
    const float* bq = (const float*)d_in[2];
    const float* Wk = (const float*)d_in[3];
    const float* bk = (const float*)d_in[4];
    const float* Wv = (const float*)d_in[5];
    const float* bv = (const float*)d_in[6];
    const float* Wo = (const float*)d_in[7];
    const float* bo = (const float*)d_in[8];
    const float* pe = (const float*)d_in[9];
    // d_in[10]: causal mask (j > i) — structural, unused

    short* xb   = (short*)d_ws;                         //  4 MB
    short* Wqb  = xb   + (size_t)BTt * Dd;              //  2 MB
    short* Wkb  = Wqb  + (size_t)Dd * Dd;               //  2 MB
    short* Wvb  = Wkb  + (size_t)Dd * Dd;               //  2 MB
    short* Wob  = Wvb  + (size_t)Dd * Dd;               //  2 MB
    short* Qb   = Wob  + (size_t)Dd * Dd;               //  4 MB
    short* Kb   = Qb   + (size_t)BTt * Dd;              //  4 MB
    short* Vrow = Kb   + (size_t)BTt * Dd;              //  4 MB
    short* Vtg  = Vrow + (size_t)BTt * Dd;              //  4 MB
    short* AOb  = Vtg  + (size_t)BTt * Dd;              //  4 MB

    dim3 gc(BTt * Dd / 8 / 256, 5);
    conv_bf16<<<gc, 256, 0, stream>>>(x, Wq, Wk, Wv, Wo, xb, Wqb, Wkb, Wvb, Wob);

    dim3 gq(BTt / 128, Dd / 64, 3);
    gemm_qkv<<<gq, 256, 0, stream>>>(xb, Wqb, Wkb, Wvb, bq, bk, bv, Qb, Kb, Vrow);

    dim3 gv(Tt / 64, Dd / 64, 2);
    v_transpose<<<gv, 256, 0, stream>>>(Vrow, Vtg);

    dim3 ga(Tt / 32 / 2, Hh, 2);   // paired i-tiles: block bx does (31-bx) then bx
    cope_attn<<<ga, 256, 0, stream>>>(Qb, Kb, Vtg, pe, AOb);

    dim3 go(BTt / 128, Dd / 64, 1);
    gemm_o<<<go, 256, 0, stream>>>(AOb, Wob, bo, (float*)d_out);
}

// Round 5
// 178.696 us; speedup vs baseline: 1.2330x; 1.0128x over previous
//
#include <hip/hip_runtime.h>
#include <math.h>

#define Tt 1024
#define Dd 1024
#define Hh 16
#define DHh 64
#define MAXPOS 64
#define BTt 2048

typedef short short8 __attribute__((ext_vector_type(8)));
typedef float floatx4 __attribute__((ext_vector_type(4)));

#define MFMA16 __builtin_amdgcn_mfma_f32_16x16x32_bf16

__device__ __forceinline__ unsigned short f2bf(float f) {
    unsigned u;
    __builtin_memcpy(&u, &f, 4);
    u = (u + 0x7FFFu + ((u >> 16) & 1u)) >> 16;
    return (unsigned short)u;
}
__device__ __forceinline__ float bf2fs(short s) {
    unsigned u = ((unsigned)(unsigned short)s) << 16;
    float f;
    __builtin_memcpy(&f, &u, 4);
    return f;
}
// fast sigmoid: v_rcp_f32 instead of IEEE div (~1 ulp; threshold margin is 4x)
__device__ __forceinline__ float fsigm(float x) {
    return __builtin_amdgcn_rcpf(1.f + __expf(-x));
}
// async global->LDS DMA, 16B/lane. LDS dest is wave-uniform base + lane*16;
// global src is per-lane. (m97 staging pattern; compiler never auto-emits this.)
__device__ __forceinline__ void gl2lds16(const short* __restrict__ g, short* l) {
    __builtin_amdgcn_global_load_lds(
        (const __attribute__((address_space(1))) void*)g,
        (__attribute__((address_space(3))) void*)l,
        16, 0, 0);
}

// ---------------- fp32 -> bf16 pre-conversion (x + 4 weights) -------------------
__global__ __launch_bounds__(256) void conv_bf16(
    const float* __restrict__ x,  const float* __restrict__ W0,
    const float* __restrict__ W1, const float* __restrict__ W2,
    const float* __restrict__ W3,
    short* __restrict__ xb, short* __restrict__ w0b, short* __restrict__ w1b,
    short* __restrict__ w2b, short* __restrict__ w3b)
{
    const float* src; short* dst; int n;
    switch (blockIdx.y) {
        case 0:  src = x;  dst = xb;  n = BTt * Dd; break;
        case 1:  src = W0; dst = w0b; n = Dd * Dd;  break;
        case 2:  src = W1; dst = w1b; n = Dd * Dd;  break;
        case 3:  src = W2; dst = w2b; n = Dd * Dd;  break;
        default: src = W3; dst = w3b; n = Dd * Dd;  break;
    }
    int idx = (blockIdx.x * 256 + threadIdx.x) * 8;
    if (idx >= n) return;
    floatx4 a0 = *(const floatx4*)&src[idx];
    floatx4 a1 = *(const floatx4*)&src[idx + 4];
    short8 s;
    for (int e = 0; e < 4; ++e) {
        s[e]     = (short)f2bf(a0[e]);
        s[e + 4] = (short)f2bf(a1[e]);
    }
    *(short8*)&dst[idx] = s;
}

// ------------- MFMA GEMM: C = A[M,K] * W[N,K]^T + bias (bf16 in, bf16 MFMA)
// R16: T3 "minimum 2-phase" double-buffered DMA staging. Per K-step: issue
// STAGE(t+1) into buf^1 FIRST (async, stays in flight), then ds_read+MFMA from
// buf, then ONE __syncthreads (drains vmcnt -> next buf ready; also fences the
// buffer recycle, which has a full barrier between last read and next write).
// vs R15: staging latency now hides under compute; barriers per step 2 -> 1.
// TMW: tile rows = TMW*64. qkv: TMW=2 (128x64, dbuf LDS 48KB, 3 blk/CU, grid
// 768 = exactly 3/CU). gemm_o: TMW=1 (64x64, 32KB, grid 512 = 2/CU; was 1/CU).
template <int MODE, int TMW>   // MODE 0: fp32 out, 1: bf16 out
__device__ __forceinline__ void gemm_body(const short* __restrict__ A,
                                          const short* __restrict__ W,
                                          const float* __restrict__ bias,
                                          void* __restrict__ Cout,
                                          int N, int K)
{
    __shared__ __align__(16) short Ash[2][TMW * 64 * 64];
    __shared__ __align__(16) short Bsh[2][64 * 64];
    const int t = threadIdx.x;
    const int lane = t & 63, wave = t >> 6;
    const int quad = lane >> 4, l16 = lane & 15;
    const int row0 = blockIdx.x * (TMW * 64), col0 = blockIdx.y * 64;

    // per-lane source coords within an 8-row DMA stripe
    const int g_r = lane >> 3, g_c = (lane & 7) * 8;

    floatx4 acc[TMW][4];
    for (int a = 0; a < TMW; ++a)
        for (int b2 = 0; b2 < 4; ++b2)
            acc[a][b2] = (floatx4){0.f, 0.f, 0.f, 0.f};

#define STAGE(buf, kb)                                                      \
    do {                                                                    \
        for (int i = 0; i < TMW * 2; ++i) {                                 \
            int rbase = (wave * (TMW * 2) + i) * 8;                         \
            gl2lds16(&A[(size_t)(row0 + rbase + g_r) * K + (kb) + g_c],     \
                     &Ash[buf][rbase * 64]);                                \
        }                                                                   \
        for (int i = 0; i < 2; ++i) {                                       \
            int rbase = (wave * 2 + i) * 8;                                 \
            gl2lds16(&W[(size_t)(col0 + rbase + g_r) * K + (kb) + g_c],     \
                     &Bsh[buf][rbase * 64]);                                \
        }                                                                   \
    } while (0)

    const int NT = K / 64;
    STAGE(0, 0);
    __syncthreads();                       // buf0 ready
    for (int ts = 0; ts < NT; ++ts) {
        const int cur = ts & 1;
        if (ts + 1 < NT) STAGE(cur ^ 1, (ts + 1) * 64);   // async, in flight
        for (int ks = 0; ks < 2; ++ks) {
            short8 af[TMW], bfr[4];
            for (int tm = 0; tm < TMW; ++tm)
                af[tm] = *(short8*)&Ash[cur][(wave * (TMW * 16) + tm * 16 + l16) * 64 + ks * 32 + quad * 8];
            for (int tn = 0; tn < 4; ++tn)
                bfr[tn] = *(short8*)&Bsh[cur][(tn * 16 + l16) * 64 + ks * 32 + quad * 8];
            for (int tm = 0; tm < TMW; ++tm)
                for (int tn = 0; tn < 4; ++tn)
                    acc[tm][tn] = MFMA16(af[tm], bfr[tn], acc[tm][tn], 0, 0, 0);
        }
        if (ts + 1 < NT) __syncthreads();  // next buf ready; recycle fenced
    }
#undef STAGE
    for (int tm = 0; tm < TMW; ++tm)
        for (int tn = 0; tn < 4; ++tn) {
            int col = col0 + tn * 16 + l16;
            float bv = bias[col];
            for (int r = 0; r < 4; ++r) {
                int row = row0 + wave * (TMW * 16) + tm * 16 + quad * 4 + r;
                float v = acc[tm][tn][r] + bv;
                if (MODE == 0) ((float*)Cout)[(size_t)row * N + col] = v;
                else           ((short*)Cout)[(size_t)row * N + col] = (short)f2bf(v);
            }
        }
}

__global__ __launch_bounds__(256) void gemm_qkv(
    const short* __restrict__ xb,
    const short* __restrict__ Wqb, const short* __restrict__ Wkb,
    const short* __restrict__ Wvb,
    const float* __restrict__ bq, const float* __restrict__ bk,
    const float* __restrict__ bv,
    short* __restrict__ Qb, short* __restrict__ Kb, short* __restrict__ Vrow)
{
    if (blockIdx.z == 0)      gemm_body<1, 2>(xb, Wqb, bq, Qb, Dd, Dd);
    else if (blockIdx.z == 1) gemm_body<1, 2>(xb, Wkb, bk, Kb, Dd, Dd);
    else                      gemm_body<1, 2>(xb, Wvb, bv, Vrow, Dd, Dd);
}

__global__ __launch_bounds__(256) void gemm_o(
    const short* __restrict__ A, const short* __restrict__ W,
    const float* __restrict__ bias, float* __restrict__ C)
{
    gemm_body<0, 1>(A, W, bias, C, Dd, Dd);
}

// ---------------- V transpose: Vt[b][d][j] = Vrow[b][j][d], 64x64 tiles ---------
__global__ __launch_bounds__(256) void v_transpose(
    const short* __restrict__ Vrow, short* __restrict__ Vt)
{
    __shared__ __align__(16) short L[64 * 72];
    const int t = threadIdx.x;
    const int j0 = blockIdx.x * 64, d0 = blockIdx.y * 64, b = blockIdx.z;
    for (int s = 0; s < 2; ++s) {
        int c = t * 2 + s;
        int jr = c >> 3, c8 = c & 7;
        *(short8*)&L[jr * 72 + c8 * 8] =
            *(const short8*)&Vrow[((size_t)(b * Tt + j0 + jr)) * Dd + d0 + c8 * 8];
    }
    __syncthreads();
    for (int s = 0; s < 2; ++s) {
        int c = t * 2 + s;
        int dr = c >> 3, c8 = c & 7;
        short8 v;
        for (int e = 0; e < 8; ++e) v[e] = L[(c8 * 8 + e) * 72 + dr];
        *(short8*)&Vt[((size_t)(b * Dd + d0 + dr)) * Tt + j0 + c8 * 8] = v;
    }
}

// ---------------- fused attn: scores + no-max softmax + PV (single pass) --------
// R14: REVERSE j-sweep (suffix gate sums on the fly, no pre-pass).
// R13 pairing: block bx does i-tile (31-bx) then bx (9 j-tiles/block).
__global__ __launch_bounds__(256) void cope_attn(
    const short* __restrict__ Q, const short* __restrict__ K,
    const short* __restrict__ Vt, const float* __restrict__ PE,
    short* __restrict__ AOb)
{
    const int h = blockIdx.y, b = blockIdx.z;
    const int t = threadIdx.x, lane = t & 63, wave = t >> 6;
    const int quad = lane >> 4, l16 = lane & 15;

    // SldS: setup Q tile (short) / S tile (f32, row stride 132 floats) /
    //       P tile (bf16, packed, aliased) -- 16.9 KB
    __shared__ __align__(16) short SldS[32 * 264];
    __shared__ __align__(16) short KV[128 * 72];    // PE / K[128][72] / V[64][136]
    __shared__ short qpeB[32 * 68];
    __shared__ float lrow[32];
    float* Sld = (float*)SldS;

    const float inv_scale = 0.125f;
    const int sr = t >> 3, ss = t & 7;

    for (int phase = 0; phase < 2; ++phase) {
        const int it = (phase == 0) ? (31 - (int)blockIdx.x) : (int)blockIdx.x;
        const int i0 = it * 32;
        const int irow = i0 + sr;

        short* QtS = SldS;
        {
            int r = t >> 3, c = t & 7;
            *(short8*)&QtS[r * 72 + c * 8] =
                *(const short8*)&Q[((size_t)(b * Tt + i0 + r)) * Dd + h * DHh + c * 8];
        }
        for (int e = 0; e < 16; ++e) {
            int idx = t + 256 * e;
            int p = idx >> 6, d = idx & 63;
            KV[p * 72 + d] = (short)f2bf(PE[((size_t)h * MAXPOS + p) * DHh + d]);
        }
        __syncthreads();

        short8 qa[2][2];
        for (int rb = 0; rb < 2; ++rb)
            for (int ks = 0; ks < 2; ++ks)
                qa[rb][ks] = *(short8*)&QtS[(rb * 16 + l16) * 72 + ks * 32 + quad * 8];

        // qpe table via MFMA (M=32, N=64, K=64)
        {
            int mt = wave >> 1;
            int ntA = 2 * (wave & 1), ntB = ntA + 1;
            floatx4 c0f = {0, 0, 0, 0}, c1f = {0, 0, 0, 0};
            for (int ks = 0; ks < 2; ++ks) {
                short8 b0 = *(short8*)&KV[(ntA * 16 + l16) * 72 + ks * 32 + quad * 8];
                short8 b1 = *(short8*)&KV[(ntB * 16 + l16) * 72 + ks * 32 + quad * 8];
                c0f = MFMA16(qa[mt][ks], b0, c0f, 0, 0, 0);
                c1f = MFMA16(qa[mt][ks], b1, c1f, 0, 0, 0);
            }
            for (int r = 0; r < 4; ++r) {
                qpeB[(mt * 16 + quad * 4 + r) * 68 + ntA * 16 + l16] = (short)f2bf(c0f[r]);
                qpeB[(mt * 16 + quad * 4 + r) * 68 + ntB * 16 + l16] = (short)f2bf(c1f[r]);
            }
        }

        const int JT = (i0 + 159) >> 7;
        floatx4 o0 = {0, 0, 0, 0}, o1 = {0, 0, 0, 0};
        const int pv_mt = wave >> 1;
        const int pv_ntA = 2 * (wave & 1), pv_ntB = pv_ntA + 1;
        float l_acc = 0.f;
        float rightAcc = 0.f;     // sum of gates in tiles already processed (k > current tile)

        short8 kreg[4];
        for (int e = 0; e < 4; ++e) {
            int ch = t + 256 * e;
            int jr = ch >> 3, c = ch & 7;
            kreg[e] = *(const short8*)&K[((size_t)(b * Tt + (JT - 1) * 128 + jr)) * Dd + h * DHh + c * 8];
        }

        for (int jt = JT - 1; jt >= 0; --jt) {
            const int j0 = jt * 128;
            __syncthreads();                                    // A: KV free
            for (int e = 0; e < 4; ++e) {
                int ch = t + 256 * e;
                int jr = ch >> 3, c = ch & 7;
                *(short8*)&KV[jr * 72 + c * 8] = kreg[e];
            }
            __syncthreads();                                    // B: K staged
            {
                int ntA = 2 * wave, ntB = ntA + 1;
                floatx4 c00 = {0,0,0,0}, c01 = {0,0,0,0}, c10 = {0,0,0,0}, c11 = {0,0,0,0};
                for (int ks = 0; ks < 2; ++ks) {
                    short8 b0 = *(short8*)&KV[(ntA * 16 + l16) * 72 + ks * 32 + quad * 8];
                    short8 b1 = *(short8*)&KV[(ntB * 16 + l16) * 72 + ks * 32 + quad * 8];
                    c00 = MFMA16(qa[0][ks], b0, c00, 0, 0, 0);
                    c01 = MFMA16(qa[0][ks], b1, c01, 0, 0, 0);
                    c10 = MFMA16(qa[1][ks], b0, c10, 0, 0, 0);
                    c11 = MFMA16(qa[1][ks], b1, c11, 0, 0, 0);
                }
                for (int r = 0; r < 4; ++r) {
                    Sld[(quad * 4 + r) * 132 + ntA * 16 + l16] = c00[r];
                    Sld[(quad * 4 + r) * 132 + ntB * 16 + l16] = c01[r];
                    Sld[(16 + quad * 4 + r) * 132 + ntA * 16 + l16] = c10[r];
                    Sld[(16 + quad * 4 + r) * 132 + ntB * 16 + l16] = c11[r];
                }
            }
            __syncthreads();                                    // C: S ready
            short8 vreg[4];
            for (int e = 0; e < 4; ++e) {
                int ch = t + 256 * e;
                int d = ch >> 4, c = ch & 15;
                vreg[e] = *(const short8*)&Vt[((size_t)(b * Dd + h * DHh + d)) * Tt + j0 + c * 8];
            }
            if (jt > 0) {
                for (int e = 0; e < 4; ++e) {
                    int ch = t + 256 * e;
                    int jr = ch >> 3, c = ch & 7;
                    kreg[e] = *(const short8*)&K[((size_t)(b * Tt + j0 - 128 + jr)) * Dd + h * DHh + c * 8];
                }
            }
            {
                // read own 16 S floats (short-typed loads, bit-cast: TBAA-safe alias)
                floatx4 qv[4];
                for (int q4 = 0; q4 < 4; ++q4) {
                    short8 qraw = *(short8*)&SldS[sr * 264 + ss * 32 + q4 * 8];
                    __builtin_memcpy(&qv[q4], &qraw, 16);
                }
                float gt[16];
                float gs = 0.f;
                for (int e = 0; e < 16; ++e) {
                    int j = j0 + ss * 16 + e;
                    float qk = qv[e >> 2][e & 3];
                    float g = (j <= irow) ? fsigm(qk * inv_scale) : 0.f;
                    gt[e] = g;
                    gs += g;
                }
                // inclusive suffix-scan of group sums across the 8 ss-groups
                float inc = gs;
                for (int d2 = 1; d2 < 8; d2 <<= 1) {
                    float n = __shfl_down(inc, d2, 64);
                    if ((lane & 7) + d2 < 8) inc += n;
                }
                // tile-row total lives at ss=0; broadcast within the row group
                float tileTot = __shfl(inc, lane & 56, 64);
                float base = rightAcc + (inc - gs);   // gates strictly right of this group
                float run = 0.f;                      // suffix within group (exclusive)
                short8 p0, p1;
                for (int e = 15; e >= 0; --e) {
                    int j = j0 + ss * 16 + e;
                    float pos = base + run;           // = sum_{k > j} g_k
                    run += gt[e];
                    pos = fminf(fmaxf(pos, 0.f), 63.f);
                    float pf = floorf(pos);
                    float al = pos - pf;
                    int fi = (int)pf;
                    int ci = fi + 1; if (ci > 63) ci = 63;
                    float qp = (1.f - al) * bf2fs(qpeB[sr * 68 + fi]) + al * bf2fs(qpeB[sr * 68 + ci]);
                    float qk = qv[e >> 2][e & 3];
                    float p = (j <= irow) ? __expf((qk + qp) * inv_scale) : 0.f;
                    if (e < 8) p0[e] = (short)f2bf(p); else p1[e - 8] = (short)f2bf(p);
                    l_acc += p;
                }
                // P overwrites the low half of this thread's OWN consumed S region
                *(short8*)&SldS[sr * 264 + ss * 32]     = p0;
                *(short8*)&SldS[sr * 264 + ss * 32 + 8] = p1;
                rightAcc += tileTot;
            }
            for (int e = 0; e < 4; ++e) {
                int ch = t + 256 * e;
                int d = ch >> 4, c = ch & 15;
                *(short8*)&KV[d * 136 + c * 8] = vreg[e];
            }
            __syncthreads();                                    // D: P + V ready
            for (int ks = 0; ks < 4; ++ks) {
                short8 a  = *(short8*)&SldS[(pv_mt * 16 + l16) * 264 + ks * 64
                                            + ((quad >> 1) << 5) + ((quad & 1) << 3)];
                short8 b0 = *(short8*)&KV[(pv_ntA * 16 + l16) * 136 + ks * 32 + quad * 8];
                short8 b1 = *(short8*)&KV[(pv_ntB * 16 + l16) * 136 + ks * 32 + quad * 8];
                o0 = MFMA16(a, b0, o0, 0, 0, 0);
                o1 = MFMA16(a, b1, o1, 0, 0, 0);
            }
        }
        float lr = l_acc;
        for (int d2 = 4; d2 >= 1; d2 >>= 1) lr += __shfl_xor(lr, d2, 64);
        if (ss == 0) lrow[sr] = lr;
        __syncthreads();
        for (int r = 0; r < 4; ++r) {
            int row = pv_mt * 16 + quad * 4 + r;
            float inv = __builtin_amdgcn_rcpf(lrow[row]);
            size_t off = ((size_t)(b * Tt + i0 + row)) * Dd + h * DHh;
            AOb[off + pv_ntA * 16 + l16] = (short)f2bf(o0[r] * inv);
            AOb[off + pv_ntB * 16 + l16] = (short)f2bf(o1[r] * inv);
        }
    }
}

// ---------------- launch ---------------------------------------------------------
extern "C" void kernel_launch(void* const* d_in, const int* in_sizes, int n_in,
                              void* d_out, int out_size, void* d_ws, size_t ws_size,
                              hipStream_t stream)
{
    const float* x  = (const float*)d_in[0];
    const float* Wq = (const float*)d_in[1];
    const float* bq = (const float*)d_in[2];
    const float* Wk = (const float*)d_in[3];
    const float* bk = (const float*)d_in[4];
    const float* Wv = (const float*)d_in[5];
    const float* bv = (const float*)d_in[6];
    const float* Wo = (const float*)d_in[7];
    const float* bo = (const float*)d_in[8];
    const float* pe = (const float*)d_in[9];
    // d_in[10]: causal mask (j > i) — structural, unused

    short* xb   = (short*)d_ws;                         //  4 MB
    short* Wqb  = xb   + (size_t)BTt * Dd;              //  2 MB
    short* Wkb  = Wqb  + (size_t)Dd * Dd;               //  2 MB
    short* Wvb  = Wkb  + (size_t)Dd * Dd;               //  2 MB
    short* Wob  = Wvb  + (size_t)Dd * Dd;               //  2 MB
    short* Qb   = Wob  + (size_t)Dd * Dd;               //  4 MB
    short* Kb   = Qb   + (size_t)BTt * Dd;              //  4 MB
    short* Vrow = Kb   + (size_t)BTt * Dd;              //  4 MB
    short* Vtg  = Vrow + (size_t)BTt * Dd;              //  4 MB
    short* AOb  = Vtg  + (size_t)BTt * Dd;              //  4 MB

    dim3 gc(BTt * Dd / 8 / 256, 5);
    conv_bf16<<<gc, 256, 0, stream>>>(x, Wq, Wk, Wv, Wo, xb, Wqb, Wkb, Wvb, Wob);

    dim3 gq(BTt / 128, Dd / 64, 3);
    gemm_qkv<<<gq, 256, 0, stream>>>(xb, Wqb, Wkb, Wvb, bq, bk, bv, Qb, Kb, Vrow);

    dim3 gv(Tt / 64, Dd / 64, 2);
    v_transpose<<<gv, 256, 0, stream>>>(Vrow, Vtg);

    dim3 ga(Tt / 32 / 2, Hh, 2);   // paired i-tiles: block bx does (31-bx) then bx
    cope_attn<<<ga, 256, 0, stream>>>(Qb, Kb, Vtg, pe, AOb);

    dim3 go(BTt / 64, Dd / 64, 1);
    gemm_o<<<go, 256, 0, stream>>>(AOb, Wob, bo, (float*)d_out);
}